// Round 1
// baseline (2066.127 us; speedup 1.0000x reference)
//
#include <hip/hip_runtime.h>
#include <cfloat>
#include <cmath>

#define NB 8
#define CC 128
#define HH 45
#define WW 60
#define HWP 2700      // H*W
#define KNN 16
#define H0 360
#define W0 480

// ---------------------------------------------------------------------------
// 1) Transpose (N,128,HW) -> (N,HW,128) channel-last
// ---------------------------------------------------------------------------
__global__ void transpose_cl(const float* __restrict__ in, float* __restrict__ out) {
    __shared__ float tile[32][33];
    int n = blockIdx.z;
    int c0 = blockIdx.y * 32;
    int p0 = blockIdx.x * 32;
    int tx = threadIdx.x & 31, ty = threadIdx.x >> 5;   // 32 x 8
    #pragma unroll
    for (int r = 0; r < 32; r += 8) {
        int c = c0 + ty + r, p = p0 + tx;
        tile[ty + r][tx] = (p < HWP) ? in[((size_t)n * CC + c) * HWP + p] : 0.f;
    }
    __syncthreads();
    #pragma unroll
    for (int r = 0; r < 32; r += 8) {
        int p = p0 + ty + r, c = c0 + tx;
        if (p < HWP) out[((size_t)n * HWP + p) * CC + c] = tile[tx][ty + r];
    }
}

// ---------------------------------------------------------------------------
// 2) Median pool 8x8 (lower median = sorted[31]), one wave64 per block
//    plane c: 0 = xy ch0, 1 = xy ch1, 2 = original ch3 (depth)
// ---------------------------------------------------------------------------
__global__ void median_pool(const float* __restrict__ xy, const float* __restrict__ orig,
                            float* __restrict__ proj) {
    int w = blockIdx.x * 4 + (threadIdx.x >> 6);
    int lane = threadIdx.x & 63;
    int n = w / (3 * HWP);
    int rem = w % (3 * HWP);
    int c = rem / HWP;
    int b = rem % HWP;
    const float* src = (c < 2) ? (xy + ((size_t)n * 2 + c) * H0 * W0)
                               : (orig + ((size_t)n * 4 + 3) * H0 * W0);
    int by = b / WW, bx = b % WW;
    int r = lane >> 3, col = lane & 7;
    float v = src[(by * 8 + r) * W0 + bx * 8 + col];
    int rank = 0;
    #pragma unroll
    for (int j = 0; j < 64; ++j) {
        float vj = __shfl(v, j, 64);
        rank += (vj < v) || (vj == v && j < lane);
    }
    if (rank == 31) proj[(size_t)c * (NB * HWP) + (size_t)n * HWP + b] = v;
}

// ---------------------------------------------------------------------------
// 3) KNN: per row i, 16 smallest D over 2700 candidates, lower-index ties.
// ---------------------------------------------------------------------------
__global__ void __launch_bounds__(256) knn_kernel(const float* __restrict__ proj,
                                                  int* __restrict__ knn) {
#pragma clang fp contract(off)
    __shared__ float sx[HWP], sy[HWP], sz[HWP], sq[HWP];
    int n = blockIdx.x / 11, chunk = blockIdx.x % 11;
    const float* px = proj + (size_t)n * HWP;
    const float* py = proj + (size_t)NB * HWP + (size_t)n * HWP;
    const float* pz = proj + (size_t)2 * NB * HWP + (size_t)n * HWP;
    for (int t = threadIdx.x; t < HWP; t += 256) {
        float x = px[t], y = py[t], z = pz[t];
        sx[t] = x; sy[t] = y; sz[t] = z;
        sq[t] = (x * x + y * y) + z * z;     // mirrors jnp.sum(proj*proj,-1)
    }
    __syncthreads();
    int i = chunk * 256 + (int)threadIdx.x;
    if (i >= HWP) return;
    float xi = sx[i], yi = sy[i], zi = sz[i], sqi = sq[i];
    float best[KNN]; int bidx[KNN];
    #pragma unroll
    for (int k = 0; k < KNN; ++k) { best[k] = FLT_MAX; bidx[k] = 0; }
    #pragma unroll 2
    for (int j = 0; j < HWP; ++j) {
        // r like a K=3 fma-accumulated dot; s without contraction
        float r = fmaf(zi, sz[j], fmaf(yi, sy[j], xi * sx[j]));
        float s = (sqi + sq[j]) - 2.0f * r;
        float d = sqrtf(fmaxf(s, 0.f));
        if (d < best[KNN - 1]) {             // strict <: keeps earlier index on ties
            float cd = d; int ci = j;
            #pragma unroll
            for (int k = 0; k < KNN; ++k) {
                bool lt = cd < best[k];
                float tv = best[k]; int ti = bidx[k];
                best[k] = lt ? cd : best[k];
                bidx[k] = lt ? ci : bidx[k];
                cd = lt ? tv : cd;
                ci = lt ? ti : ci;
            }
        }
    }
    #pragma unroll
    for (int k = 0; k < KNN; ++k)
        knn[((size_t)n * HWP + i) * KNN + k] = bidx[k];
}

// ---------------------------------------------------------------------------
// 4) GEMM + bias + PReLU: out[r][c] = prelu(sum_k A[r][k]*Wt[c][k] + b[c])
//    A = [A0 | A1] (each 128 wide). Block: 32 rows x 128 cols, thread 4x4.
// ---------------------------------------------------------------------------
template <int K>
__global__ void __launch_bounds__(256) gemm_prelu(
    const float* __restrict__ A0, const float* __restrict__ A1,
    const float* __restrict__ Wt, const float* __restrict__ bias,
    const float* __restrict__ alphap, float* __restrict__ out) {
    __shared__ float As[32][K + 4];
    __shared__ float Ws[32][132];            // chunk of 32 k, stored [k][c]
    int r0 = blockIdx.x * 32;
    int tid = threadIdx.x;
    {   // stage A tile (full K) — all reads of own rows precede writes => in-place safe
        constexpr int TOT = 32 * K / 4;
        for (int t = tid; t < TOT; t += 256) {
            int row = t / (K / 4);
            int k = (t % (K / 4)) * 4;
            const float* src = (K == 256 && k >= 128)
                                   ? (A1 + ((size_t)(r0 + row)) * 128 + (k - 128))
                                   : (A0 + ((size_t)(r0 + row)) * 128 + k);
            *(float4*)&As[row][k] = *(const float4*)src;
        }
    }
    int cg = tid & 31, rg = tid >> 5;
    int c0 = cg * 4;
    float acc[4][4] = {};
    for (int k0 = 0; k0 < K; k0 += 32) {
        __syncthreads();
        #pragma unroll
        for (int it = 0; it < 4; ++it) {     // stage W chunk transposed [k][c]
            int linear = it * 256 + tid;
            int c = linear >> 3, k4 = linear & 7;
            float4 v = *(const float4*)&Wt[(size_t)c * K + k0 + k4 * 4];
            Ws[k4 * 4 + 0][c] = v.x; Ws[k4 * 4 + 1][c] = v.y;
            Ws[k4 * 4 + 2][c] = v.z; Ws[k4 * 4 + 3][c] = v.w;
        }
        __syncthreads();
        #pragma unroll
        for (int k = 0; k < 32; k += 4) {
            float4 a4[4], w4[4];
            #pragma unroll
            for (int i = 0; i < 4; ++i) a4[i] = *(const float4*)&As[rg * 4 + i][k0 + k];
            #pragma unroll
            for (int kk = 0; kk < 4; ++kk) w4[kk] = *(const float4*)&Ws[k + kk][c0];
            #pragma unroll
            for (int i = 0; i < 4; ++i) {
                float av[4] = {a4[i].x, a4[i].y, a4[i].z, a4[i].w};
                #pragma unroll
                for (int kk = 0; kk < 4; ++kk) {
                    acc[i][0] += av[kk] * w4[kk].x;
                    acc[i][1] += av[kk] * w4[kk].y;
                    acc[i][2] += av[kk] * w4[kk].z;
                    acc[i][3] += av[kk] * w4[kk].w;
                }
            }
        }
    }
    float alpha = alphap[0];
    float4 bv = *(const float4*)&bias[c0];
    float bb[4] = {bv.x, bv.y, bv.z, bv.w};
    #pragma unroll
    for (int i = 0; i < 4; ++i) {
        float4 o;
        float* op = (float*)&o;
        #pragma unroll
        for (int j = 0; j < 4; ++j) {
            float v = acc[i][j] + bb[j];
            op[j] = (v >= 0.f) ? v : alpha * v;
        }
        *(float4*)&out[((size_t)(r0 + rg * 4 + i)) * 128 + c0] = o;
    }
}

// ---------------------------------------------------------------------------
// 5) gather + mean over 16 neighbors
// ---------------------------------------------------------------------------
__global__ void gather_mean(const float* __restrict__ g, const int* __restrict__ knn,
                            float* __restrict__ m) {
    int tid = threadIdx.x;
    int rloc = tid >> 5, c4 = tid & 31;
    size_t row = (size_t)blockIdx.x * 8 + rloc;
    int n = (int)(row / HWP);
    const int* kn = knn + row * KNN;
    float4 acc = {0, 0, 0, 0};
    #pragma unroll
    for (int k = 0; k < KNN; ++k) {
        int j = kn[k];
        float4 v = *(const float4*)&g[((size_t)n * HWP + j) * 128 + c4 * 4];
        acc.x += v.x; acc.y += v.y; acc.z += v.z; acc.w += v.w;
    }
    const float s = 1.f / 16.f;
    float4 o = {acc.x * s, acc.y * s, acc.z * s, acc.w * s};
    *(float4*)&m[row * 128 + c4 * 4] = o;
}

// ---------------------------------------------------------------------------
// 6) 3x3 conv, 256 -> 128 ch, pad 1. Block = (oc-half, y, n), 128 threads.
//    Thread tile: 4 oc x 8 px, ic chunks of 8 staged in LDS.
// ---------------------------------------------------------------------------
__global__ void __launch_bounds__(128) conv3x3(
    const float* __restrict__ cl0,   // channels 0..127   (cnn channel-last)
    const float* __restrict__ cl1,   // channels 128..255 (h channel-last)
    const float* __restrict__ w,     // (128,256,3,3)
    const float* __restrict__ bias,
    float* __restrict__ out) {       // (N,128,45,60)
    __shared__ float in_lds[3 * 66 * 9];     // [ky][xi 0..65][ic 0..7] (ic stride 9)
    __shared__ float w_lds[72 * 68];         // [(ic*9+tap)][ocl], row stride 68
    int ochalf = blockIdx.x;
    int y = blockIdx.y;
    int n = blockIdx.z;
    int tid = threadIdx.x;
    int ocg = tid >> 3, pxg = tid & 7;
    int ocl0 = ocg * 4;
    int oc0 = ochalf * 64 + ocl0;
    int x0 = pxg * 8;
    float acc[4][8] = {};
    for (int icc = 0; icc < 32; ++icc) {
        int ch = icc * 8;
        const float* src = (ch < 128) ? cl0 : cl1;
        int ch0 = ch & 127;
        __syncthreads();
        for (int t = tid; t < 396; t += 128) {   // 3 * 66 * 2 float4 groups
            int ky = t / 132, r2 = t % 132;
            int xi = r2 >> 1, half = r2 & 1;
            int yy = y + ky - 1, xx = xi - 1;
            float4 v = {0, 0, 0, 0};
            if (yy >= 0 && yy < HH && xx >= 0 && xx < WW)
                v = *(const float4*)&src[(((size_t)n * HWP) + yy * WW + xx) * 128 + ch0 + half * 4];
            float* dst = &in_lds[(ky * 66 + xi) * 9 + half * 4];
            dst[0] = v.x; dst[1] = v.y; dst[2] = v.z; dst[3] = v.w;
        }
        for (int t = tid; t < 4608; t += 128) {  // 64 oc x 8 ic x 9 taps
            int oc = t / 72, rem = t % 72;
            int ic = rem / 9, tap = rem % 9;
            w_lds[(ic * 9 + tap) * 68 + oc] =
                w[((size_t)(ochalf * 64 + oc)) * 2304 + (ch + ic) * 9 + tap];
        }
        __syncthreads();
        #pragma unroll
        for (int ic = 0; ic < 8; ++ic) {
            float4 wv[9];
            #pragma unroll
            for (int tap = 0; tap < 9; ++tap)
                wv[tap] = *(const float4*)&w_lds[(ic * 9 + tap) * 68 + ocl0];
            #pragma unroll
            for (int ky = 0; ky < 3; ++ky) {
                float av[10];
                #pragma unroll
                for (int q = 0; q < 10; ++q) av[q] = in_lds[(ky * 66 + x0 + q) * 9 + ic];
                #pragma unroll
                for (int kx = 0; kx < 3; ++kx) {
                    float4 wq = wv[ky * 3 + kx];
                    #pragma unroll
                    for (int p = 0; p < 8; ++p) {
                        float a = av[p + kx];
                        acc[0][p] += a * wq.x;
                        acc[1][p] += a * wq.y;
                        acc[2][p] += a * wq.z;
                        acc[3][p] += a * wq.w;
                    }
                }
            }
        }
    }
    #pragma unroll
    for (int j = 0; j < 4; ++j) {
        float b = bias[oc0 + j];
        #pragma unroll
        for (int p = 0; p < 8; ++p) {
            int x = x0 + p;
            if (x < WW)
                out[(((size_t)n * 128 + oc0 + j) * HH + y) * WW + x] = acc[j][p] + b;
        }
    }
}

// ---------------------------------------------------------------------------
extern "C" void kernel_launch(void* const* d_in, const int* in_sizes, int n_in,
                              void* d_out, int out_size, void* d_ws, size_t ws_size,
                              hipStream_t stream) {
    const float* cnn    = (const float*)d_in[0];
    const float* orig   = (const float*)d_in[1];
    const float* xy     = (const float*)d_in[2];
    const float* g_w0   = (const float*)d_in[3];
    const float* g_b0   = (const float*)d_in[4];
    const float* g_a0   = (const float*)d_in[5];
    const float* g_w1   = (const float*)d_in[6];
    const float* g_b1   = (const float*)d_in[7];
    const float* g_a1   = (const float*)d_in[8];
    const float* q_w    = (const float*)d_in[9];
    const float* q_b    = (const float*)d_in[10];
    const float* q_a    = (const float*)d_in[11];
    const float* conv_w = (const float*)d_in[12];
    const float* conv_b = (const float*)d_in[13];
    float* out = (float*)d_out;

    float* ws = (float*)d_ws;
    const size_t S = (size_t)NB * HWP * CC;     // 2,764,800
    float* cnn_cl = ws;
    float* h      = ws + S;
    float* tg     = ws + 2 * S;
    float* m      = ws + 3 * S;
    float* proj   = ws + 4 * S;                 // 3 * N*HW
    int*   knn    = (int*)(ws + 4 * S + (size_t)3 * NB * HWP);

    transpose_cl<<<dim3(85, 4, NB), 256, 0, stream>>>(cnn, cnn_cl);
    median_pool<<<16200, 256, 0, stream>>>(xy, orig, proj);
    knn_kernel<<<88, 256, 0, stream>>>(proj, knn);

    // GNN iteration 1 (h = cnn_cl)
    gemm_prelu<128><<<675, 256, 0, stream>>>(cnn_cl, nullptr, g_w0, g_b0, g_a0, tg);
    gemm_prelu<128><<<675, 256, 0, stream>>>(tg, nullptr, g_w1, g_b1, g_a1, tg);
    gather_mean<<<2700, 256, 0, stream>>>(tg, knn, m);
    gemm_prelu<256><<<675, 256, 0, stream>>>(cnn_cl, m, q_w, q_b, q_a, h);

    // GNN iteration 2
    gemm_prelu<128><<<675, 256, 0, stream>>>(h, nullptr, g_w0, g_b0, g_a0, tg);
    gemm_prelu<128><<<675, 256, 0, stream>>>(tg, nullptr, g_w1, g_b1, g_a1, tg);
    gather_mean<<<2700, 256, 0, stream>>>(tg, knn, m);
    gemm_prelu<256><<<675, 256, 0, stream>>>(h, m, q_w, q_b, q_a, h);

    conv3x3<<<dim3(2, HH, NB), 128, 0, stream>>>(cnn_cl, h, conv_w, conv_b, out);
}

// Round 2
// 1304.099 us; speedup vs baseline: 1.5843x; 1.5843x over previous
//
#include <hip/hip_runtime.h>
#include <cfloat>
#include <cmath>

#define NB 8
#define CC 128
#define HH 45
#define WW 60
#define HWP 2700      // H*W
#define KNN 16
#define H0 360
#define W0 480

// ---------------------------------------------------------------------------
// 1) Transpose (N,128,HW) -> (N,HW,128) channel-last
// ---------------------------------------------------------------------------
__global__ void transpose_cl(const float* __restrict__ in, float* __restrict__ out) {
    __shared__ float tile[32][33];
    int n = blockIdx.z;
    int c0 = blockIdx.y * 32;
    int p0 = blockIdx.x * 32;
    int tx = threadIdx.x & 31, ty = threadIdx.x >> 5;   // 32 x 8
    #pragma unroll
    for (int r = 0; r < 32; r += 8) {
        int c = c0 + ty + r, p = p0 + tx;
        tile[ty + r][tx] = (p < HWP) ? in[((size_t)n * CC + c) * HWP + p] : 0.f;
    }
    __syncthreads();
    #pragma unroll
    for (int r = 0; r < 32; r += 8) {
        int p = p0 + ty + r, c = c0 + tx;
        if (p < HWP) out[((size_t)n * HWP + p) * CC + c] = tile[tx][ty + r];
    }
}

// ---------------------------------------------------------------------------
// 2) Median pool 8x8 (lower median = sorted[31]), one wave64 per block
// ---------------------------------------------------------------------------
__global__ void median_pool(const float* __restrict__ xy, const float* __restrict__ orig,
                            float* __restrict__ proj) {
    int w = blockIdx.x * 4 + (threadIdx.x >> 6);
    int lane = threadIdx.x & 63;
    int n = w / (3 * HWP);
    int rem = w % (3 * HWP);
    int c = rem / HWP;
    int b = rem % HWP;
    const float* src = (c < 2) ? (xy + ((size_t)n * 2 + c) * H0 * W0)
                               : (orig + ((size_t)n * 4 + 3) * H0 * W0);
    int by = b / WW, bx = b % WW;
    int r = lane >> 3, col = lane & 7;
    float v = src[(by * 8 + r) * W0 + bx * 8 + col];
    int rank = 0;
    #pragma unroll
    for (int j = 0; j < 64; ++j) {
        float vj = __shfl(v, j, 64);
        rank += (vj < v) || (vj == v && j < lane);
    }
    if (rank == 31) proj[(size_t)c * (NB * HWP) + (size_t)n * HWP + b] = v;
}

// ---------------------------------------------------------------------------
// 3) KNN — one wave64 per row. Lanes partition candidates j = lane + 64*t,
//    keep lane-local sorted top-16 (stable, strict <), then 16-step
//    wave-argmin-pop merge on the (d, j) lexicographic pair.
//    Distance arithmetic bit-identical to the validated round-1 kernel.
// ---------------------------------------------------------------------------
__global__ void __launch_bounds__(256) knn_kernel(const float* __restrict__ proj,
                                                  int* __restrict__ knn) {
#pragma clang fp contract(off)
    __shared__ float4 pts[HWP];              // (x, y, z, sq) per candidate
    int n = blockIdx.y;
    const float* px = proj + (size_t)n * HWP;
    const float* py = proj + (size_t)NB * HWP + (size_t)n * HWP;
    const float* pz = proj + (size_t)2 * NB * HWP + (size_t)n * HWP;
    for (int t = threadIdx.x; t < HWP; t += 256) {
        float x = px[t], y = py[t], z = pz[t];
        float4 p;
        p.x = x; p.y = y; p.z = z;
        p.w = (x * x + y * y) + z * z;       // mirrors jnp.sum(proj*proj,-1)
        pts[t] = p;
    }
    __syncthreads();

    int wave = threadIdx.x >> 6;
    int lane = threadIdx.x & 63;
    int i = blockIdx.x * 4 + wave;           // row (675*4 == 2700 exactly)
    float4 pi = pts[i];
    float xi = pi.x, yi = pi.y, zi = pi.z, sqi = pi.w;

    float best[KNN]; int bidx[KNN];
    #pragma unroll
    for (int k = 0; k < KNN; ++k) { best[k] = FLT_MAX; bidx[k] = 0x7fffffff; }

    for (int j = lane; j < HWP; j += 64) {
        float4 pj = pts[j];
        float r = fmaf(zi, pj.z, fmaf(yi, pj.y, xi * pj.x));
        float s = (sqi + pj.w) - 2.0f * r;
        float d = sqrtf(fmaxf(s, 0.f));
        if (d < best[KNN - 1]) {             // strict <: stable (earlier j wins ties)
            float cd = d; int ci = j;
            #pragma unroll
            for (int k = 0; k < KNN; ++k) {
                bool lt = cd < best[k];
                float tv = best[k]; int ti = bidx[k];
                best[k] = lt ? cd : best[k];
                bidx[k] = lt ? ci : bidx[k];
                cd = lt ? tv : cd;
                ci = lt ? ti : ci;
            }
        }
    }

    // Merge 64 sorted lane-lists: 16 rounds of wave-wide argmin(d, j) + pop.
    int myj = 0;
    float hd = best[0]; int hj = bidx[0];
    #pragma unroll
    for (int t = 0; t < KNN; ++t) {
        float md = hd; int mj = hj;
        #pragma unroll
        for (int off = 32; off >= 1; off >>= 1) {
            float od = __shfl_xor(md, off, 64);
            int oj = __shfl_xor(mj, off, 64);
            if (od < md || (od == md && oj < mj)) { md = od; mj = oj; }
        }
        if (lane == t) myj = mj;
        bool win = (hd == md) && (hj == mj);   // unique: j's partitioned by lane
        if (win) {
            #pragma unroll
            for (int k = 0; k < KNN - 1; ++k) { best[k] = best[k + 1]; bidx[k] = bidx[k + 1]; }
            best[KNN - 1] = FLT_MAX; bidx[KNN - 1] = 0x7fffffff;
            hd = best[0]; hj = bidx[0];
        }
    }
    if (lane < KNN)
        knn[((size_t)n * HWP + i) * KNN + lane] = myj;
}

// ---------------------------------------------------------------------------
// 4) GEMM + bias + PReLU: out[r][c] = prelu(sum_k A[r][k]*Wt[c][k] + b[c])
//    A = [A0 | A1] (each 128 wide). Block: 32 rows x 128 cols, thread 4x4.
// ---------------------------------------------------------------------------
template <int K>
__global__ void __launch_bounds__(256) gemm_prelu(
    const float* __restrict__ A0, const float* __restrict__ A1,
    const float* __restrict__ Wt, const float* __restrict__ bias,
    const float* __restrict__ alphap, float* __restrict__ out) {
    __shared__ float As[32][K + 4];
    __shared__ float Ws[32][132];            // chunk of 32 k, stored [k][c]
    int r0 = blockIdx.x * 32;
    int tid = threadIdx.x;
    {   // stage A tile (full K)
        constexpr int TOT = 32 * K / 4;
        for (int t = tid; t < TOT; t += 256) {
            int row = t / (K / 4);
            int k = (t % (K / 4)) * 4;
            const float* src = (K == 256 && k >= 128)
                                   ? (A1 + ((size_t)(r0 + row)) * 128 + (k - 128))
                                   : (A0 + ((size_t)(r0 + row)) * 128 + k);
            *(float4*)&As[row][k] = *(const float4*)src;
        }
    }
    int cg = tid & 31, rg = tid >> 5;
    int c0 = cg * 4;
    float acc[4][4] = {};
    for (int k0 = 0; k0 < K; k0 += 32) {
        __syncthreads();
        #pragma unroll
        for (int it = 0; it < 4; ++it) {     // stage W chunk transposed [k][c]
            int linear = it * 256 + tid;
            int c = linear >> 3, k4 = linear & 7;
            float4 v = *(const float4*)&Wt[(size_t)c * K + k0 + k4 * 4];
            Ws[k4 * 4 + 0][c] = v.x; Ws[k4 * 4 + 1][c] = v.y;
            Ws[k4 * 4 + 2][c] = v.z; Ws[k4 * 4 + 3][c] = v.w;
        }
        __syncthreads();
        #pragma unroll
        for (int k = 0; k < 32; k += 4) {
            float4 a4[4], w4[4];
            #pragma unroll
            for (int i = 0; i < 4; ++i) a4[i] = *(const float4*)&As[rg * 4 + i][k0 + k];
            #pragma unroll
            for (int kk = 0; kk < 4; ++kk) w4[kk] = *(const float4*)&Ws[k + kk][c0];
            #pragma unroll
            for (int i = 0; i < 4; ++i) {
                float av[4] = {a4[i].x, a4[i].y, a4[i].z, a4[i].w};
                #pragma unroll
                for (int kk = 0; kk < 4; ++kk) {
                    acc[i][0] += av[kk] * w4[kk].x;
                    acc[i][1] += av[kk] * w4[kk].y;
                    acc[i][2] += av[kk] * w4[kk].z;
                    acc[i][3] += av[kk] * w4[kk].w;
                }
            }
        }
    }
    float alpha = alphap[0];
    float4 bv = *(const float4*)&bias[c0];
    float bb[4] = {bv.x, bv.y, bv.z, bv.w};
    #pragma unroll
    for (int i = 0; i < 4; ++i) {
        float4 o;
        float* op = (float*)&o;
        #pragma unroll
        for (int j = 0; j < 4; ++j) {
            float v = acc[i][j] + bb[j];
            op[j] = (v >= 0.f) ? v : alpha * v;
        }
        *(float4*)&out[((size_t)(r0 + rg * 4 + i)) * 128 + c0] = o;
    }
}

// ---------------------------------------------------------------------------
// 5) gather + mean over 16 neighbors
// ---------------------------------------------------------------------------
__global__ void gather_mean(const float* __restrict__ g, const int* __restrict__ knn,
                            float* __restrict__ m) {
    int tid = threadIdx.x;
    int rloc = tid >> 5, c4 = tid & 31;
    size_t row = (size_t)blockIdx.x * 8 + rloc;
    int n = (int)(row / HWP);
    const int* kn = knn + row * KNN;
    float4 acc = {0, 0, 0, 0};
    #pragma unroll
    for (int k = 0; k < KNN; ++k) {
        int j = kn[k];
        float4 v = *(const float4*)&g[((size_t)n * HWP + j) * 128 + c4 * 4];
        acc.x += v.x; acc.y += v.y; acc.z += v.z; acc.w += v.w;
    }
    const float s = 1.f / 16.f;
    float4 o = {acc.x * s, acc.y * s, acc.z * s, acc.w * s};
    *(float4*)&m[row * 128 + c4 * 4] = o;
}

// ---------------------------------------------------------------------------
// 6) 3x3 conv, 256 -> 128 ch, pad 1. Block = (oc-half, y, n), 128 threads.
// ---------------------------------------------------------------------------
__global__ void __launch_bounds__(128) conv3x3(
    const float* __restrict__ cl0,   // channels 0..127   (cnn channel-last)
    const float* __restrict__ cl1,   // channels 128..255 (h channel-last)
    const float* __restrict__ w,     // (128,256,3,3)
    const float* __restrict__ bias,
    float* __restrict__ out) {       // (N,128,45,60)
    __shared__ float in_lds[3 * 66 * 9];     // [ky][xi 0..65][ic 0..7] (ic stride 9)
    __shared__ float w_lds[72 * 68];         // [(ic*9+tap)][ocl], row stride 68
    int ochalf = blockIdx.x;
    int y = blockIdx.y;
    int n = blockIdx.z;
    int tid = threadIdx.x;
    int ocg = tid >> 3, pxg = tid & 7;
    int ocl0 = ocg * 4;
    int oc0 = ochalf * 64 + ocl0;
    int x0 = pxg * 8;
    float acc[4][8] = {};
    for (int icc = 0; icc < 32; ++icc) {
        int ch = icc * 8;
        const float* src = (ch < 128) ? cl0 : cl1;
        int ch0 = ch & 127;
        __syncthreads();
        for (int t = tid; t < 396; t += 128) {   // 3 * 66 * 2 float4 groups
            int ky = t / 132, r2 = t % 132;
            int xi = r2 >> 1, half = r2 & 1;
            int yy = y + ky - 1, xx = xi - 1;
            float4 v = {0, 0, 0, 0};
            if (yy >= 0 && yy < HH && xx >= 0 && xx < WW)
                v = *(const float4*)&src[(((size_t)n * HWP) + yy * WW + xx) * 128 + ch0 + half * 4];
            float* dst = &in_lds[(ky * 66 + xi) * 9 + half * 4];
            dst[0] = v.x; dst[1] = v.y; dst[2] = v.z; dst[3] = v.w;
        }
        for (int t = tid; t < 4608; t += 128) {  // 64 oc x 8 ic x 9 taps
            int oc = t / 72, rem = t % 72;
            int ic = rem / 9, tap = rem % 9;
            w_lds[(ic * 9 + tap) * 68 + oc] =
                w[((size_t)(ochalf * 64 + oc)) * 2304 + (ch + ic) * 9 + tap];
        }
        __syncthreads();
        #pragma unroll
        for (int ic = 0; ic < 8; ++ic) {
            float4 wv[9];
            #pragma unroll
            for (int tap = 0; tap < 9; ++tap)
                wv[tap] = *(const float4*)&w_lds[(ic * 9 + tap) * 68 + ocl0];
            #pragma unroll
            for (int ky = 0; ky < 3; ++ky) {
                float av[10];
                #pragma unroll
                for (int q = 0; q < 10; ++q) av[q] = in_lds[(ky * 66 + x0 + q) * 9 + ic];
                #pragma unroll
                for (int kx = 0; kx < 3; ++kx) {
                    float4 wq = wv[ky * 3 + kx];
                    #pragma unroll
                    for (int p = 0; p < 8; ++p) {
                        float a = av[p + kx];
                        acc[0][p] += a * wq.x;
                        acc[1][p] += a * wq.y;
                        acc[2][p] += a * wq.z;
                        acc[3][p] += a * wq.w;
                    }
                }
            }
        }
    }
    #pragma unroll
    for (int j = 0; j < 4; ++j) {
        float b = bias[oc0 + j];
        #pragma unroll
        for (int p = 0; p < 8; ++p) {
            int x = x0 + p;
            if (x < WW)
                out[(((size_t)n * 128 + oc0 + j) * HH + y) * WW + x] = acc[j][p] + b;
        }
    }
}

// ---------------------------------------------------------------------------
extern "C" void kernel_launch(void* const* d_in, const int* in_sizes, int n_in,
                              void* d_out, int out_size, void* d_ws, size_t ws_size,
                              hipStream_t stream) {
    const float* cnn    = (const float*)d_in[0];
    const float* orig   = (const float*)d_in[1];
    const float* xy     = (const float*)d_in[2];
    const float* g_w0   = (const float*)d_in[3];
    const float* g_b0   = (const float*)d_in[4];
    const float* g_a0   = (const float*)d_in[5];
    const float* g_w1   = (const float*)d_in[6];
    const float* g_b1   = (const float*)d_in[7];
    const float* g_a1   = (const float*)d_in[8];
    const float* q_w    = (const float*)d_in[9];
    const float* q_b    = (const float*)d_in[10];
    const float* q_a    = (const float*)d_in[11];
    const float* conv_w = (const float*)d_in[12];
    const float* conv_b = (const float*)d_in[13];
    float* out = (float*)d_out;

    float* ws = (float*)d_ws;
    const size_t S = (size_t)NB * HWP * CC;     // 2,764,800
    float* cnn_cl = ws;
    float* h      = ws + S;
    float* tg     = ws + 2 * S;
    float* m      = ws + 3 * S;
    float* proj   = ws + 4 * S;                 // 3 * N*HW
    int*   knn    = (int*)(ws + 4 * S + (size_t)3 * NB * HWP);

    transpose_cl<<<dim3(85, 4, NB), 256, 0, stream>>>(cnn, cnn_cl);
    median_pool<<<16200, 256, 0, stream>>>(xy, orig, proj);
    knn_kernel<<<dim3(675, NB), 256, 0, stream>>>(proj, knn);

    // GNN iteration 1 (h = cnn_cl)
    gemm_prelu<128><<<675, 256, 0, stream>>>(cnn_cl, nullptr, g_w0, g_b0, g_a0, tg);
    gemm_prelu<128><<<675, 256, 0, stream>>>(tg, nullptr, g_w1, g_b1, g_a1, tg);
    gather_mean<<<2700, 256, 0, stream>>>(tg, knn, m);
    gemm_prelu<256><<<675, 256, 0, stream>>>(cnn_cl, m, q_w, q_b, q_a, h);

    // GNN iteration 2
    gemm_prelu<128><<<675, 256, 0, stream>>>(h, nullptr, g_w0, g_b0, g_a0, tg);
    gemm_prelu<128><<<675, 256, 0, stream>>>(tg, nullptr, g_w1, g_b1, g_a1, tg);
    gather_mean<<<2700, 256, 0, stream>>>(tg, knn, m);
    gemm_prelu<256><<<675, 256, 0, stream>>>(h, m, q_w, q_b, q_a, h);

    conv3x3<<<dim3(2, HH, NB), 128, 0, stream>>>(cnn_cl, h, conv_w, conv_b, out);
}

// Round 3
// 590.862 us; speedup vs baseline: 3.4968x; 2.2071x over previous
//
#include <hip/hip_runtime.h>
#include <cfloat>
#include <cmath>

#define NB 8
#define CC 128
#define HH 45
#define WW 60
#define HWP 2700      // H*W
#define KNN 16
#define H0 360
#define W0 480

typedef __bf16 bf16_8 __attribute__((ext_vector_type(8)));
typedef float  f32x4  __attribute__((ext_vector_type(4)));

// ---------------------------------------------------------------------------
// 1) Transpose (N,128,HW) -> (N,HW,128) channel-last
// ---------------------------------------------------------------------------
__global__ void transpose_cl(const float* __restrict__ in, float* __restrict__ out) {
    __shared__ float tile[32][33];
    int n = blockIdx.z;
    int c0 = blockIdx.y * 32;
    int p0 = blockIdx.x * 32;
    int tx = threadIdx.x & 31, ty = threadIdx.x >> 5;   // 32 x 8
    #pragma unroll
    for (int r = 0; r < 32; r += 8) {
        int c = c0 + ty + r, p = p0 + tx;
        tile[ty + r][tx] = (p < HWP) ? in[((size_t)n * CC + c) * HWP + p] : 0.f;
    }
    __syncthreads();
    #pragma unroll
    for (int r = 0; r < 32; r += 8) {
        int p = p0 + ty + r, c = c0 + tx;
        if (p < HWP) out[((size_t)n * HWP + p) * CC + c] = tile[tx][ty + r];
    }
}

// ---------------------------------------------------------------------------
// 2) Median pool 8x8 (lower median = sorted[31]), one wave64 per block
// ---------------------------------------------------------------------------
__global__ void median_pool(const float* __restrict__ xy, const float* __restrict__ orig,
                            float* __restrict__ proj) {
    int w = blockIdx.x * 4 + (threadIdx.x >> 6);
    int lane = threadIdx.x & 63;
    int n = w / (3 * HWP);
    int rem = w % (3 * HWP);
    int c = rem / HWP;
    int b = rem % HWP;
    const float* src = (c < 2) ? (xy + ((size_t)n * 2 + c) * H0 * W0)
                               : (orig + ((size_t)n * 4 + 3) * H0 * W0);
    int by = b / WW, bx = b % WW;
    int r = lane >> 3, col = lane & 7;
    float v = src[(by * 8 + r) * W0 + bx * 8 + col];
    int rank = 0;
    #pragma unroll
    for (int j = 0; j < 64; ++j) {
        float vj = __shfl(v, j, 64);
        rank += (vj < v) || (vj == v && j < lane);
    }
    if (rank == 31) proj[(size_t)c * (NB * HWP) + (size_t)n * HWP + b] = v;
}

// ---------------------------------------------------------------------------
// 3) KNN — one wave64 per row (validated round 2)
// ---------------------------------------------------------------------------
__global__ void __launch_bounds__(256) knn_kernel(const float* __restrict__ proj,
                                                  int* __restrict__ knn) {
#pragma clang fp contract(off)
    __shared__ float4 pts[HWP];              // (x, y, z, sq) per candidate
    int n = blockIdx.y;
    const float* px = proj + (size_t)n * HWP;
    const float* py = proj + (size_t)NB * HWP + (size_t)n * HWP;
    const float* pz = proj + (size_t)2 * NB * HWP + (size_t)n * HWP;
    for (int t = threadIdx.x; t < HWP; t += 256) {
        float x = px[t], y = py[t], z = pz[t];
        float4 p;
        p.x = x; p.y = y; p.z = z;
        p.w = (x * x + y * y) + z * z;       // mirrors jnp.sum(proj*proj,-1)
        pts[t] = p;
    }
    __syncthreads();

    int wave = threadIdx.x >> 6;
    int lane = threadIdx.x & 63;
    int i = blockIdx.x * 4 + wave;           // row (675*4 == 2700 exactly)
    float4 pi = pts[i];
    float xi = pi.x, yi = pi.y, zi = pi.z, sqi = pi.w;

    float best[KNN]; int bidx[KNN];
    #pragma unroll
    for (int k = 0; k < KNN; ++k) { best[k] = FLT_MAX; bidx[k] = 0x7fffffff; }

    for (int j = lane; j < HWP; j += 64) {
        float4 pj = pts[j];
        float r = fmaf(zi, pj.z, fmaf(yi, pj.y, xi * pj.x));
        float s = (sqi + pj.w) - 2.0f * r;
        float d = sqrtf(fmaxf(s, 0.f));
        if (d < best[KNN - 1]) {             // strict <: stable (earlier j wins ties)
            float cd = d; int ci = j;
            #pragma unroll
            for (int k = 0; k < KNN; ++k) {
                bool lt = cd < best[k];
                float tv = best[k]; int ti = bidx[k];
                best[k] = lt ? cd : best[k];
                bidx[k] = lt ? ci : bidx[k];
                cd = lt ? tv : cd;
                ci = lt ? ti : ci;
            }
        }
    }

    // Merge 64 sorted lane-lists: 16 rounds of wave-wide argmin(d, j) + pop.
    int myj = 0;
    float hd = best[0]; int hj = bidx[0];
    #pragma unroll
    for (int t = 0; t < KNN; ++t) {
        float md = hd; int mj = hj;
        #pragma unroll
        for (int off = 32; off >= 1; off >>= 1) {
            float od = __shfl_xor(md, off, 64);
            int oj = __shfl_xor(mj, off, 64);
            if (od < md || (od == md && oj < mj)) { md = od; mj = oj; }
        }
        if (lane == t) myj = mj;
        bool win = (hd == md) && (hj == mj);   // unique: j's partitioned by lane
        if (win) {
            #pragma unroll
            for (int k = 0; k < KNN - 1; ++k) { best[k] = best[k + 1]; bidx[k] = bidx[k + 1]; }
            best[KNN - 1] = FLT_MAX; bidx[KNN - 1] = 0x7fffffff;
            hd = best[0]; hj = bidx[0];
        }
    }
    if (lane < KNN)
        knn[((size_t)n * HWP + i) * KNN + lane] = myj;
}

// ---------------------------------------------------------------------------
// 4) GEMM + bias + PReLU (fp32, unchanged)
// ---------------------------------------------------------------------------
template <int K>
__global__ void __launch_bounds__(256) gemm_prelu(
    const float* __restrict__ A0, const float* __restrict__ A1,
    const float* __restrict__ Wt, const float* __restrict__ bias,
    const float* __restrict__ alphap, float* __restrict__ out) {
    __shared__ float As[32][K + 4];
    __shared__ float Ws[32][132];            // chunk of 32 k, stored [k][c]
    int r0 = blockIdx.x * 32;
    int tid = threadIdx.x;
    {   // stage A tile (full K)
        constexpr int TOT = 32 * K / 4;
        for (int t = tid; t < TOT; t += 256) {
            int row = t / (K / 4);
            int k = (t % (K / 4)) * 4;
            const float* src = (K == 256 && k >= 128)
                                   ? (A1 + ((size_t)(r0 + row)) * 128 + (k - 128))
                                   : (A0 + ((size_t)(r0 + row)) * 128 + k);
            *(float4*)&As[row][k] = *(const float4*)src;
        }
    }
    int cg = tid & 31, rg = tid >> 5;
    int c0 = cg * 4;
    float acc[4][4] = {};
    for (int k0 = 0; k0 < K; k0 += 32) {
        __syncthreads();
        #pragma unroll
        for (int it = 0; it < 4; ++it) {     // stage W chunk transposed [k][c]
            int linear = it * 256 + tid;
            int c = linear >> 3, k4 = linear & 7;
            float4 v = *(const float4*)&Wt[(size_t)c * K + k0 + k4 * 4];
            Ws[k4 * 4 + 0][c] = v.x; Ws[k4 * 4 + 1][c] = v.y;
            Ws[k4 * 4 + 2][c] = v.z; Ws[k4 * 4 + 3][c] = v.w;
        }
        __syncthreads();
        #pragma unroll
        for (int k = 0; k < 32; k += 4) {
            float4 a4[4], w4[4];
            #pragma unroll
            for (int i = 0; i < 4; ++i) a4[i] = *(const float4*)&As[rg * 4 + i][k0 + k];
            #pragma unroll
            for (int kk = 0; kk < 4; ++kk) w4[kk] = *(const float4*)&Ws[k + kk][c0];
            #pragma unroll
            for (int i = 0; i < 4; ++i) {
                float av[4] = {a4[i].x, a4[i].y, a4[i].z, a4[i].w};
                #pragma unroll
                for (int kk = 0; kk < 4; ++kk) {
                    acc[i][0] += av[kk] * w4[kk].x;
                    acc[i][1] += av[kk] * w4[kk].y;
                    acc[i][2] += av[kk] * w4[kk].z;
                    acc[i][3] += av[kk] * w4[kk].w;
                }
            }
        }
    }
    float alpha = alphap[0];
    float4 bv = *(const float4*)&bias[c0];
    float bb[4] = {bv.x, bv.y, bv.z, bv.w};
    #pragma unroll
    for (int i = 0; i < 4; ++i) {
        float4 o;
        float* op = (float*)&o;
        #pragma unroll
        for (int j = 0; j < 4; ++j) {
            float v = acc[i][j] + bb[j];
            op[j] = (v >= 0.f) ? v : alpha * v;
        }
        *(float4*)&out[((size_t)(r0 + rg * 4 + i)) * 128 + c0] = o;
    }
}

// ---------------------------------------------------------------------------
// 5) gather + mean over 16 neighbors
// ---------------------------------------------------------------------------
__global__ void gather_mean(const float* __restrict__ g, const int* __restrict__ knn,
                            float* __restrict__ m) {
    int tid = threadIdx.x;
    int rloc = tid >> 5, c4 = tid & 31;
    size_t row = (size_t)blockIdx.x * 8 + rloc;
    int n = (int)(row / HWP);
    const int* kn = knn + row * KNN;
    float4 acc = {0, 0, 0, 0};
    #pragma unroll
    for (int k = 0; k < KNN; ++k) {
        int j = kn[k];
        float4 v = *(const float4*)&g[((size_t)n * HWP + j) * 128 + c4 * 4];
        acc.x += v.x; acc.y += v.y; acc.z += v.z; acc.w += v.w;
    }
    const float s = 1.f / 16.f;
    float4 o = {acc.x * s, acc.y * s, acc.z * s, acc.w * s};
    *(float4*)&m[row * 128 + c4 * 4] = o;
}

// ---------------------------------------------------------------------------
// 6a) Pack concat(cnn_cl, h) -> zero-padded channel-last bf16 (N,47,68,256)
// ---------------------------------------------------------------------------
__global__ void pack_input(const float* __restrict__ cnn_cl, const float* __restrict__ h,
                           __bf16* __restrict__ pad_in) {
    int t = blockIdx.x * 256 + threadIdx.x;      // 818,176 threads, 8 ch each
    int cg = t & 31;
    int s = t >> 5;
    int q = s % 68; s /= 68;
    int p = s % 47;
    int n = s / 47;
    int y = p - 1, x = q - 1;
    bf16_8 v = {};
    if (y >= 0 && y < HH && x >= 0 && x < WW) {
        int c0 = cg * 8;
        const float* src = (c0 < 128)
            ? (cnn_cl + (((size_t)n * HWP + y * WW + x) * 128 + c0))
            : (h      + (((size_t)n * HWP + y * WW + x) * 128 + (c0 - 128)));
        float4 l0 = *(const float4*)&src[0];
        float4 l1 = *(const float4*)&src[4];
        v[0] = (__bf16)l0.x; v[1] = (__bf16)l0.y; v[2] = (__bf16)l0.z; v[3] = (__bf16)l0.w;
        v[4] = (__bf16)l1.x; v[5] = (__bf16)l1.y; v[6] = (__bf16)l1.z; v[7] = (__bf16)l1.w;
    }
    ((bf16_8*)pad_in)[t] = v;
}

// ---------------------------------------------------------------------------
// 6b) Swizzle conv weights into MFMA B-fragment order:
//     w_frag[tap][icc(8)][ntile(8)][lane(64)][j(8)] bf16
//     lane: n = lane&15 (oc within tile), k = (lane>>4)*8 + j (ic within chunk)
// ---------------------------------------------------------------------------
__global__ void prep_wfrag(const float* __restrict__ conv_w, __bf16* __restrict__ w_frag) {
    int t = blockIdx.x * 256 + threadIdx.x;      // 294,912 threads
    int j = t & 7;
    int lane = (t >> 3) & 63;
    int ntile = (t >> 9) & 7;
    int icc = (t >> 12) & 7;
    int tap = t >> 15;                            // 0..8
    int oc = ntile * 16 + (lane & 15);
    int ic = icc * 32 + (lane >> 4) * 8 + j;
    w_frag[t] = (__bf16)conv_w[((size_t)oc * 256 + ic) * 9 + tap];
}

// ---------------------------------------------------------------------------
// 6c) Conv 3x3 as implicit GEMM on MFMA. Block = (y, n), 256 thr = 4 waves.
//     Wave (wm, wn): M-half (32 px) x N-half (64 oc); 2 M-tiles x 4 N-tiles.
//     K = 8 ic-chunks of 32 x 9 taps, mfma_f32_16x16x32_bf16.
// ---------------------------------------------------------------------------
__global__ void __launch_bounds__(256) conv_mfma(
    const __bf16* __restrict__ pad_in,   // (N,47,68,256)
    const __bf16* __restrict__ w_frag,   // fragment-ordered weights
    const float* __restrict__ bias,
    float* __restrict__ out) {           // (N,128,45,60)
    __shared__ __bf16 alds[3 * 66 * 32];         // [dy][px 0..65][ic 0..31]
    int y = blockIdx.x;
    int n = blockIdx.y;
    int tid = threadIdx.x;
    int wave = tid >> 6, lane = tid & 63;
    int wm = wave & 1, wn = wave >> 1;
    int quad = lane >> 4, lm = lane & 15;

    f32x4 acc[2][4] = {};
    const bf16_8* wf = (const bf16_8*)w_frag;

    for (int icc = 0; icc < 8; ++icc) {
        __syncthreads();
        // stage A window: rows y..y+2 (padded), px 0..65, 32 channels
        for (int t = tid; t < 792; t += 256) {   // 3*66*4 x 16B
            int cq = t & 3;
            int xp = (t >> 2) % 66;
            int dy = (t >> 2) / 66;
            size_t src = (((size_t)n * 47 + (y + dy)) * 68 + xp) * 256 + icc * 32 + cq * 8;
            *(bf16_8*)&alds[(dy * 66 + xp) * 32 + cq * 8] = *(const bf16_8*)&pad_in[src];
        }
        __syncthreads();
        #pragma unroll
        for (int tap = 0; tap < 9; ++tap) {
            int ky = tap / 3, kx = tap % 3;
            bf16_8 b[4], a[2];
            #pragma unroll
            for (int nt = 0; nt < 4; ++nt)
                b[nt] = wf[(((tap * 8 + icc) * 8) + (wn * 4 + nt)) * 64 + lane];
            #pragma unroll
            for (int mt = 0; mt < 2; ++mt)
                a[mt] = *(const bf16_8*)&alds[(ky * 66 + (wm * 32 + mt * 16 + lm + kx)) * 32 + quad * 8];
            #pragma unroll
            for (int mt = 0; mt < 2; ++mt)
                #pragma unroll
                for (int nt = 0; nt < 4; ++nt)
                    acc[mt][nt] = __builtin_amdgcn_mfma_f32_16x16x32_bf16(
                        a[mt], b[nt], acc[mt][nt], 0, 0, 0);
        }
    }
    // Epilogue: D row = px (quad*4 + reg, 4 consecutive), col = oc (lm)
    #pragma unroll
    for (int mt = 0; mt < 2; ++mt) {
        int x0 = wm * 32 + mt * 16 + quad * 4;
        if (x0 >= WW) continue;
        #pragma unroll
        for (int nt = 0; nt < 4; ++nt) {
            int oc = wn * 64 + nt * 16 + lm;
            float bb = bias[oc];
            f32x4 v = acc[mt][nt];
            v[0] += bb; v[1] += bb; v[2] += bb; v[3] += bb;
            *(f32x4*)&out[(((size_t)n * 128 + oc) * HH + y) * WW + x0] = v;
        }
    }
}

// ---------------------------------------------------------------------------
extern "C" void kernel_launch(void* const* d_in, const int* in_sizes, int n_in,
                              void* d_out, int out_size, void* d_ws, size_t ws_size,
                              hipStream_t stream) {
    const float* cnn    = (const float*)d_in[0];
    const float* orig   = (const float*)d_in[1];
    const float* xy     = (const float*)d_in[2];
    const float* g_w0   = (const float*)d_in[3];
    const float* g_b0   = (const float*)d_in[4];
    const float* g_a0   = (const float*)d_in[5];
    const float* g_w1   = (const float*)d_in[6];
    const float* g_b1   = (const float*)d_in[7];
    const float* g_a1   = (const float*)d_in[8];
    const float* q_w    = (const float*)d_in[9];
    const float* q_b    = (const float*)d_in[10];
    const float* q_a    = (const float*)d_in[11];
    const float* conv_w = (const float*)d_in[12];
    const float* conv_b = (const float*)d_in[13];
    float* out = (float*)d_out;

    float* ws = (float*)d_ws;
    const size_t S = (size_t)NB * HWP * CC;     // 2,764,800
    float* cnn_cl = ws;
    float* h      = ws + S;
    float* tg     = ws + 2 * S;
    float* m      = ws + 3 * S;
    float* proj   = ws + 4 * S;                 // 3 * N*HW
    int*   knn    = (int*)(ws + 4 * S + (size_t)3 * NB * HWP);
    // dead after the GNN: tg/m regions reused for conv staging
    __bf16* pad_in = (__bf16*)(ws + 2 * S);                    // 6,545,408 bf16 (3.28M fl)
    __bf16* w_frag = (__bf16*)(ws + 3 * S + 600000);           // 294,912 bf16

    transpose_cl<<<dim3(85, 4, NB), 256, 0, stream>>>(cnn, cnn_cl);
    median_pool<<<16200, 256, 0, stream>>>(xy, orig, proj);
    knn_kernel<<<dim3(675, NB), 256, 0, stream>>>(proj, knn);

    // GNN iteration 1 (h = cnn_cl)
    gemm_prelu<128><<<675, 256, 0, stream>>>(cnn_cl, nullptr, g_w0, g_b0, g_a0, tg);
    gemm_prelu<128><<<675, 256, 0, stream>>>(tg, nullptr, g_w1, g_b1, g_a1, tg);
    gather_mean<<<2700, 256, 0, stream>>>(tg, knn, m);
    gemm_prelu<256><<<675, 256, 0, stream>>>(cnn_cl, m, q_w, q_b, q_a, h);

    // GNN iteration 2
    gemm_prelu<128><<<675, 256, 0, stream>>>(h, nullptr, g_w0, g_b0, g_a0, tg);
    gemm_prelu<128><<<675, 256, 0, stream>>>(tg, nullptr, g_w1, g_b1, g_a1, tg);
    gather_mean<<<2700, 256, 0, stream>>>(tg, knn, m);
    gemm_prelu<256><<<675, 256, 0, stream>>>(h, m, q_w, q_b, q_a, h);

    // Conv: pack inputs (bf16, padded), swizzle weights, MFMA conv
    pack_input<<<3196, 256, 0, stream>>>(cnn_cl, h, pad_in);
    prep_wfrag<<<1152, 256, 0, stream>>>(conv_w, w_frag);
    conv_mfma<<<dim3(HH, NB), 256, 0, stream>>>(pad_in, w_frag, conv_b, out);
}

// Round 4
// 497.219 us; speedup vs baseline: 4.1554x; 1.1883x over previous
//
#include <hip/hip_runtime.h>
#include <cfloat>
#include <cmath>

#define NB 8
#define CC 128
#define HH 45
#define WW 60
#define HWP 2700      // H*W
#define KNN 16
#define H0 360
#define W0 480
#define NT 43         // ceil(2700/64) candidates per lane
#define SCAP 128      // survivor buffer capacity per wave

typedef __bf16 bf16_8 __attribute__((ext_vector_type(8)));
typedef float  f32x4  __attribute__((ext_vector_type(4)));

// ---------------------------------------------------------------------------
// 1) Transpose (N,128,HW) -> (N,HW,128) channel-last
// ---------------------------------------------------------------------------
__global__ void transpose_cl(const float* __restrict__ in, float* __restrict__ out) {
    __shared__ float tile[32][33];
    int n = blockIdx.z;
    int c0 = blockIdx.y * 32;
    int p0 = blockIdx.x * 32;
    int tx = threadIdx.x & 31, ty = threadIdx.x >> 5;   // 32 x 8
    #pragma unroll
    for (int r = 0; r < 32; r += 8) {
        int c = c0 + ty + r, p = p0 + tx;
        tile[ty + r][tx] = (p < HWP) ? in[((size_t)n * CC + c) * HWP + p] : 0.f;
    }
    __syncthreads();
    #pragma unroll
    for (int r = 0; r < 32; r += 8) {
        int p = p0 + ty + r, c = c0 + tx;
        if (p < HWP) out[((size_t)n * HWP + p) * CC + c] = tile[tx][ty + r];
    }
}

// ---------------------------------------------------------------------------
// 2) Median pool 8x8 (lower median = sorted[31]), one wave64 per block
// ---------------------------------------------------------------------------
__global__ void median_pool(const float* __restrict__ xy, const float* __restrict__ orig,
                            float* __restrict__ proj) {
    int w = blockIdx.x * 4 + (threadIdx.x >> 6);
    int lane = threadIdx.x & 63;
    int n = w / (3 * HWP);
    int rem = w % (3 * HWP);
    int c = rem / HWP;
    int b = rem % HWP;
    const float* src = (c < 2) ? (xy + ((size_t)n * 2 + c) * H0 * W0)
                               : (orig + ((size_t)n * 4 + 3) * H0 * W0);
    int by = b / WW, bx = b % WW;
    int r = lane >> 3, col = lane & 7;
    float v = src[(by * 8 + r) * W0 + bx * 8 + col];
    int rank = 0;
    #pragma unroll
    for (int j = 0; j < 64; ++j) {
        float vj = __shfl(v, j, 64);
        rank += (vj < v) || (vj == v && j < lane);
    }
    if (rank == 31) proj[(size_t)c * (NB * HWP) + (size_t)n * HWP + b] = v;
}

// ---------------------------------------------------------------------------
// 3) KNN — one wave64 per row, threshold-prefilter selection.
//    Pass A: distances in regs + lane min.  M = 16th-smallest of 64 lane
//    minima (bitonic), provably >= d16.  Pass B: ballot-compact survivors
//    (d <= M) as u64 keys (d_bits<<32|idx) into per-wave LDS.  Exact
//    16-round argmin-pop over survivors.  Fallback = validated full path.
// ---------------------------------------------------------------------------
__global__ void __launch_bounds__(256) knn_kernel(const float* __restrict__ proj,
                                                  int* __restrict__ knn) {
#pragma clang fp contract(off)
    __shared__ float4 pts[HWP];                    // (x, y, z, sq) per candidate
    __shared__ unsigned long long sbuf[4][SCAP];   // survivor keys per wave
    int n = blockIdx.y;
    const float* px = proj + (size_t)n * HWP;
    const float* py = proj + (size_t)NB * HWP + (size_t)n * HWP;
    const float* pz = proj + (size_t)2 * NB * HWP + (size_t)n * HWP;
    for (int t = threadIdx.x; t < HWP; t += 256) {
        float x = px[t], y = py[t], z = pz[t];
        float4 p;
        p.x = x; p.y = y; p.z = z;
        p.w = (x * x + y * y) + z * z;             // mirrors jnp.sum(proj*proj,-1)
        pts[t] = p;
    }
    __syncthreads();

    int wave = threadIdx.x >> 6;
    int lane = threadIdx.x & 63;
    int i = blockIdx.x * 4 + wave;                 // row (675*4 == 2700 exactly)
    float4 pi = pts[i];
    float xi = pi.x, yi = pi.y, zi = pi.z, sqi = pi.w;

    // ---- Pass A: distances (bit-identical math to validated kernel) ----
    float d[NT];
    float mn = FLT_MAX;
    #pragma unroll
    for (int t = 0; t < NT; ++t) {
        int j = lane + t * 64;
        float dd = FLT_MAX;
        if (j < HWP) {
            float4 pj = pts[j];
            float r = fmaf(zi, pj.z, fmaf(yi, pj.y, xi * pj.x));
            float s = (sqi + pj.w) - 2.0f * r;
            dd = sqrtf(fmaxf(s, 0.f));
        }
        d[t] = dd;
        mn = fminf(mn, dd);
    }

    // ---- Bitonic sort the 64 lane minima ascending; M = rank 15 ----
    float v = mn;
    #pragma unroll
    for (int k = 2; k <= 64; k <<= 1) {
        #pragma unroll
        for (int j2 = k >> 1; j2 >= 1; j2 >>= 1) {
            float p = __shfl_xor(v, j2, 64);
            bool dir = (lane & k) == 0;
            bool low = (lane & j2) == 0;
            v = (dir == low) ? fminf(v, p) : fmaxf(v, p);
        }
    }
    float M = __shfl(v, 15, 64);

    // ---- Pass B: ballot-compact survivors into LDS as u64 keys ----
    int cnt = 0;
    #pragma unroll
    for (int t = 0; t < NT; ++t) {
        bool pred = d[t] <= M;
        unsigned long long b = __ballot(pred);
        if (b) {
            int off = cnt + (int)__popcll(b & ((1ull << lane) - 1ull));
            if (pred && off < SCAP) {
                unsigned int j = (unsigned int)(lane + t * 64);
                sbuf[wave][off] =
                    ((unsigned long long)__float_as_uint(d[t]) << 32) | j;
            }
            cnt += (int)__popcll(b);
        }
    }

    int myj = 0;
    if (cnt >= KNN && cnt <= SCAP) {
        // ---- exact top-16 by u64 key over survivors (<=2 per lane) ----
        const unsigned long long INFK = ~0ull;
        unsigned long long h0 = (lane < cnt) ? sbuf[wave][lane] : INFK;
        unsigned long long h1 = (lane + 64 < cnt) ? sbuf[wave][lane + 64] : INFK;
        unsigned long long head = h0 < h1 ? h0 : h1;
        unsigned long long tail = h0 < h1 ? h1 : h0;
        #pragma unroll
        for (int r = 0; r < KNN; ++r) {
            unsigned long long m = head;
            #pragma unroll
            for (int off = 32; off >= 1; off >>= 1) {
                unsigned long long o = __shfl_xor(m, off, 64);
                m = (o < m) ? o : m;
            }
            if (lane == r) myj = (int)(unsigned int)(m & 0xffffffffull);
            if (head == m) { head = tail; tail = INFK; }   // unique: idx in key
        }
    } else {
        // ---- fallback: validated round-3 full scan + insert + merge ----
        float best[KNN]; int bidx[KNN];
        #pragma unroll
        for (int k = 0; k < KNN; ++k) { best[k] = FLT_MAX; bidx[k] = 0x7fffffff; }
        for (int j = lane; j < HWP; j += 64) {
            float4 pj = pts[j];
            float r = fmaf(zi, pj.z, fmaf(yi, pj.y, xi * pj.x));
            float s = (sqi + pj.w) - 2.0f * r;
            float dd = sqrtf(fmaxf(s, 0.f));
            if (dd < best[KNN - 1]) {
                float cd = dd; int ci = j;
                #pragma unroll
                for (int k = 0; k < KNN; ++k) {
                    bool lt = cd < best[k];
                    float tv = best[k]; int ti = bidx[k];
                    best[k] = lt ? cd : best[k];
                    bidx[k] = lt ? ci : bidx[k];
                    cd = lt ? tv : cd;
                    ci = lt ? ti : ci;
                }
            }
        }
        float hd = best[0]; int hj = bidx[0];
        #pragma unroll
        for (int t = 0; t < KNN; ++t) {
            float md = hd; int mj = hj;
            #pragma unroll
            for (int off = 32; off >= 1; off >>= 1) {
                float od = __shfl_xor(md, off, 64);
                int oj = __shfl_xor(mj, off, 64);
                if (od < md || (od == md && oj < mj)) { md = od; mj = oj; }
            }
            if (lane == t) myj = mj;
            bool win = (hd == md) && (hj == mj);
            if (win) {
                #pragma unroll
                for (int k = 0; k < KNN - 1; ++k) { best[k] = best[k + 1]; bidx[k] = bidx[k + 1]; }
                best[KNN - 1] = FLT_MAX; bidx[KNN - 1] = 0x7fffffff;
                hd = best[0]; hj = bidx[0];
            }
        }
    }
    if (lane < KNN)
        knn[((size_t)n * HWP + i) * KNN + lane] = myj;
}

// ---------------------------------------------------------------------------
// 4) GEMM + bias + PReLU (fp32, unchanged)
// ---------------------------------------------------------------------------
template <int K>
__global__ void __launch_bounds__(256) gemm_prelu(
    const float* __restrict__ A0, const float* __restrict__ A1,
    const float* __restrict__ Wt, const float* __restrict__ bias,
    const float* __restrict__ alphap, float* __restrict__ out) {
    __shared__ float As[32][K + 4];
    __shared__ float Ws[32][132];            // chunk of 32 k, stored [k][c]
    int r0 = blockIdx.x * 32;
    int tid = threadIdx.x;
    {   // stage A tile (full K)
        constexpr int TOT = 32 * K / 4;
        for (int t = tid; t < TOT; t += 256) {
            int row = t / (K / 4);
            int k = (t % (K / 4)) * 4;
            const float* src = (K == 256 && k >= 128)
                                   ? (A1 + ((size_t)(r0 + row)) * 128 + (k - 128))
                                   : (A0 + ((size_t)(r0 + row)) * 128 + k);
            *(float4*)&As[row][k] = *(const float4*)src;
        }
    }
    int cg = tid & 31, rg = tid >> 5;
    int c0 = cg * 4;
    float acc[4][4] = {};
    for (int k0 = 0; k0 < K; k0 += 32) {
        __syncthreads();
        #pragma unroll
        for (int it = 0; it < 4; ++it) {     // stage W chunk transposed [k][c]
            int linear = it * 256 + tid;
            int c = linear >> 3, k4 = linear & 7;
            float4 v = *(const float4*)&Wt[(size_t)c * K + k0 + k4 * 4];
            Ws[k4 * 4 + 0][c] = v.x; Ws[k4 * 4 + 1][c] = v.y;
            Ws[k4 * 4 + 2][c] = v.z; Ws[k4 * 4 + 3][c] = v.w;
        }
        __syncthreads();
        #pragma unroll
        for (int k = 0; k < 32; k += 4) {
            float4 a4[4], w4[4];
            #pragma unroll
            for (int i = 0; i < 4; ++i) a4[i] = *(const float4*)&As[rg * 4 + i][k0 + k];
            #pragma unroll
            for (int kk = 0; kk < 4; ++kk) w4[kk] = *(const float4*)&Ws[k + kk][c0];
            #pragma unroll
            for (int i = 0; i < 4; ++i) {
                float av[4] = {a4[i].x, a4[i].y, a4[i].z, a4[i].w};
                #pragma unroll
                for (int kk = 0; kk < 4; ++kk) {
                    acc[i][0] += av[kk] * w4[kk].x;
                    acc[i][1] += av[kk] * w4[kk].y;
                    acc[i][2] += av[kk] * w4[kk].z;
                    acc[i][3] += av[kk] * w4[kk].w;
                }
            }
        }
    }
    float alpha = alphap[0];
    float4 bv = *(const float4*)&bias[c0];
    float bb[4] = {bv.x, bv.y, bv.z, bv.w};
    #pragma unroll
    for (int i = 0; i < 4; ++i) {
        float4 o;
        float* op = (float*)&o;
        #pragma unroll
        for (int j = 0; j < 4; ++j) {
            float v = acc[i][j] + bb[j];
            op[j] = (v >= 0.f) ? v : alpha * v;
        }
        *(float4*)&out[((size_t)(r0 + rg * 4 + i)) * 128 + c0] = o;
    }
}

// ---------------------------------------------------------------------------
// 5) gather + mean over 16 neighbors
// ---------------------------------------------------------------------------
__global__ void gather_mean(const float* __restrict__ g, const int* __restrict__ knn,
                            float* __restrict__ m) {
    int tid = threadIdx.x;
    int rloc = tid >> 5, c4 = tid & 31;
    size_t row = (size_t)blockIdx.x * 8 + rloc;
    int n = (int)(row / HWP);
    const int* kn = knn + row * KNN;
    float4 acc = {0, 0, 0, 0};
    #pragma unroll
    for (int k = 0; k < KNN; ++k) {
        int j = kn[k];
        float4 v = *(const float4*)&g[((size_t)n * HWP + j) * 128 + c4 * 4];
        acc.x += v.x; acc.y += v.y; acc.z += v.z; acc.w += v.w;
    }
    const float s = 1.f / 16.f;
    float4 o = {acc.x * s, acc.y * s, acc.z * s, acc.w * s};
    *(float4*)&m[row * 128 + c4 * 4] = o;
}

// ---------------------------------------------------------------------------
// 6a) Pack concat(cnn_cl, h) -> zero-padded channel-last bf16 (N,47,68,256)
// ---------------------------------------------------------------------------
__global__ void pack_input(const float* __restrict__ cnn_cl, const float* __restrict__ h,
                           __bf16* __restrict__ pad_in) {
    int t = blockIdx.x * 256 + threadIdx.x;      // 818,176 threads, 8 ch each
    int cg = t & 31;
    int s = t >> 5;
    int q = s % 68; s /= 68;
    int p = s % 47;
    int n = s / 47;
    int y = p - 1, x = q - 1;
    bf16_8 v = {};
    if (y >= 0 && y < HH && x >= 0 && x < WW) {
        int c0 = cg * 8;
        const float* src = (c0 < 128)
            ? (cnn_cl + (((size_t)n * HWP + y * WW + x) * 128 + c0))
            : (h      + (((size_t)n * HWP + y * WW + x) * 128 + (c0 - 128)));
        float4 l0 = *(const float4*)&src[0];
        float4 l1 = *(const float4*)&src[4];
        v[0] = (__bf16)l0.x; v[1] = (__bf16)l0.y; v[2] = (__bf16)l0.z; v[3] = (__bf16)l0.w;
        v[4] = (__bf16)l1.x; v[5] = (__bf16)l1.y; v[6] = (__bf16)l1.z; v[7] = (__bf16)l1.w;
    }
    ((bf16_8*)pad_in)[t] = v;
}

// ---------------------------------------------------------------------------
// 6b) Swizzle conv weights into MFMA B-fragment order
// ---------------------------------------------------------------------------
__global__ void prep_wfrag(const float* __restrict__ conv_w, __bf16* __restrict__ w_frag) {
    int t = blockIdx.x * 256 + threadIdx.x;      // 294,912 threads
    int j = t & 7;
    int lane = (t >> 3) & 63;
    int ntile = (t >> 9) & 7;
    int icc = (t >> 12) & 7;
    int tap = t >> 15;                            // 0..8
    int oc = ntile * 16 + (lane & 15);
    int ic = icc * 32 + (lane >> 4) * 8 + j;
    w_frag[t] = (__bf16)conv_w[((size_t)oc * 256 + ic) * 9 + tap];
}

// ---------------------------------------------------------------------------
// 6c) Conv 3x3 as implicit GEMM on MFMA (validated round 3)
// ---------------------------------------------------------------------------
__global__ void __launch_bounds__(256) conv_mfma(
    const __bf16* __restrict__ pad_in,   // (N,47,68,256)
    const __bf16* __restrict__ w_frag,   // fragment-ordered weights
    const float* __restrict__ bias,
    float* __restrict__ out) {           // (N,128,45,60)
    __shared__ __bf16 alds[3 * 66 * 32];         // [dy][px 0..65][ic 0..31]
    int y = blockIdx.x;
    int n = blockIdx.y;
    int tid = threadIdx.x;
    int wave = tid >> 6, lane = tid & 63;
    int wm = wave & 1, wn = wave >> 1;
    int quad = lane >> 4, lm = lane & 15;

    f32x4 acc[2][4] = {};
    const bf16_8* wf = (const bf16_8*)w_frag;

    for (int icc = 0; icc < 8; ++icc) {
        __syncthreads();
        for (int t = tid; t < 792; t += 256) {   // 3*66*4 x 16B
            int cq = t & 3;
            int xp = (t >> 2) % 66;
            int dy = (t >> 2) / 66;
            size_t src = (((size_t)n * 47 + (y + dy)) * 68 + xp) * 256 + icc * 32 + cq * 8;
            *(bf16_8*)&alds[(dy * 66 + xp) * 32 + cq * 8] = *(const bf16_8*)&pad_in[src];
        }
        __syncthreads();
        #pragma unroll
        for (int tap = 0; tap < 9; ++tap) {
            int ky = tap / 3, kx = tap % 3;
            bf16_8 b[4], a[2];
            #pragma unroll
            for (int nt = 0; nt < 4; ++nt)
                b[nt] = wf[(((tap * 8 + icc) * 8) + (wn * 4 + nt)) * 64 + lane];
            #pragma unroll
            for (int mt = 0; mt < 2; ++mt)
                a[mt] = *(const bf16_8*)&alds[(ky * 66 + (wm * 32 + mt * 16 + lm + kx)) * 32 + quad * 8];
            #pragma unroll
            for (int mt = 0; mt < 2; ++mt)
                #pragma unroll
                for (int nt = 0; nt < 4; ++nt)
                    acc[mt][nt] = __builtin_amdgcn_mfma_f32_16x16x32_bf16(
                        a[mt], b[nt], acc[mt][nt], 0, 0, 0);
        }
    }
    #pragma unroll
    for (int mt = 0; mt < 2; ++mt) {
        int x0 = wm * 32 + mt * 16 + quad * 4;
        if (x0 >= WW) continue;
        #pragma unroll
        for (int nt = 0; nt < 4; ++nt) {
            int oc = wn * 64 + nt * 16 + lm;
            float bb = bias[oc];
            f32x4 v = acc[mt][nt];
            v[0] += bb; v[1] += bb; v[2] += bb; v[3] += bb;
            *(f32x4*)&out[(((size_t)n * 128 + oc) * HH + y) * WW + x0] = v;
        }
    }
}

// ---------------------------------------------------------------------------
extern "C" void kernel_launch(void* const* d_in, const int* in_sizes, int n_in,
                              void* d_out, int out_size, void* d_ws, size_t ws_size,
                              hipStream_t stream) {
    const float* cnn    = (const float*)d_in[0];
    const float* orig   = (const float*)d_in[1];
    const float* xy     = (const float*)d_in[2];
    const float* g_w0   = (const float*)d_in[3];
    const float* g_b0   = (const float*)d_in[4];
    const float* g_a0   = (const float*)d_in[5];
    const float* g_w1   = (const float*)d_in[6];
    const float* g_b1   = (const float*)d_in[7];
    const float* g_a1   = (const float*)d_in[8];
    const float* q_w    = (const float*)d_in[9];
    const float* q_b    = (const float*)d_in[10];
    const float* q_a    = (const float*)d_in[11];
    const float* conv_w = (const float*)d_in[12];
    const float* conv_b = (const float*)d_in[13];
    float* out = (float*)d_out;

    float* ws = (float*)d_ws;
    const size_t S = (size_t)NB * HWP * CC;     // 2,764,800
    float* cnn_cl = ws;
    float* h      = ws + S;
    float* tg     = ws + 2 * S;
    float* m      = ws + 3 * S;
    float* proj   = ws + 4 * S;                 // 3 * N*HW
    int*   knn    = (int*)(ws + 4 * S + (size_t)3 * NB * HWP);
    // dead after the GNN: tg/m regions reused for conv staging
    __bf16* pad_in = (__bf16*)(ws + 2 * S);                    // 6,545,408 bf16
    __bf16* w_frag = (__bf16*)(ws + 3 * S + 600000);           // 294,912 bf16

    transpose_cl<<<dim3(85, 4, NB), 256, 0, stream>>>(cnn, cnn_cl);
    median_pool<<<16200, 256, 0, stream>>>(xy, orig, proj);
    knn_kernel<<<dim3(675, NB), 256, 0, stream>>>(proj, knn);

    // GNN iteration 1 (h = cnn_cl)
    gemm_prelu<128><<<675, 256, 0, stream>>>(cnn_cl, nullptr, g_w0, g_b0, g_a0, tg);
    gemm_prelu<128><<<675, 256, 0, stream>>>(tg, nullptr, g_w1, g_b1, g_a1, tg);
    gather_mean<<<2700, 256, 0, stream>>>(tg, knn, m);
    gemm_prelu<256><<<675, 256, 0, stream>>>(cnn_cl, m, q_w, q_b, q_a, h);

    // GNN iteration 2
    gemm_prelu<128><<<675, 256, 0, stream>>>(h, nullptr, g_w0, g_b0, g_a0, tg);
    gemm_prelu<128><<<675, 256, 0, stream>>>(tg, nullptr, g_w1, g_b1, g_a1, tg);
    gather_mean<<<2700, 256, 0, stream>>>(tg, knn, m);
    gemm_prelu<256><<<675, 256, 0, stream>>>(h, m, q_w, q_b, q_a, h);

    // Conv: pack inputs (bf16, padded), swizzle weights, MFMA conv
    pack_input<<<3196, 256, 0, stream>>>(cnn_cl, h, pad_in);
    prep_wfrag<<<1152, 256, 0, stream>>>(conv_w, w_frag);
    conv_mfma<<<dim3(HH, NB), 256, 0, stream>>>(pad_in, w_frag, conv_b, out);
}

// Round 5
// 343.927 us; speedup vs baseline: 6.0075x; 1.4457x over previous
//
#include <hip/hip_runtime.h>
#include <cfloat>
#include <cmath>

#define NB 8
#define CC 128
#define HH 45
#define WW 60
#define HWP 2700      // H*W
#define KNN 16
#define H0 360
#define W0 480
#define NT 43         // ceil(2700/64) candidates per lane
#define MROWS 21600   // NB * HWP

typedef __bf16 bf16_8 __attribute__((ext_vector_type(8)));
typedef __bf16 bf16_4 __attribute__((ext_vector_type(4)));
typedef float  f32x4  __attribute__((ext_vector_type(4)));

// ---------------------------------------------------------------------------
// 1) Transpose (N,128,HW) -> (N,HW,128) channel-last
// ---------------------------------------------------------------------------
__global__ void transpose_cl(const float* __restrict__ in, float* __restrict__ out) {
    __shared__ float tile[32][33];
    int n = blockIdx.z;
    int c0 = blockIdx.y * 32;
    int p0 = blockIdx.x * 32;
    int tx = threadIdx.x & 31, ty = threadIdx.x >> 5;   // 32 x 8
    #pragma unroll
    for (int r = 0; r < 32; r += 8) {
        int c = c0 + ty + r, p = p0 + tx;
        tile[ty + r][tx] = (p < HWP) ? in[((size_t)n * CC + c) * HWP + p] : 0.f;
    }
    __syncthreads();
    #pragma unroll
    for (int r = 0; r < 32; r += 8) {
        int p = p0 + ty + r, c = c0 + tx;
        if (p < HWP) out[((size_t)n * HWP + p) * CC + c] = tile[tx][ty + r];
    }
}

// ---------------------------------------------------------------------------
// 2) Median pool 8x8: bitonic sort 64 lanes ascending, lane 31 = lower median
// ---------------------------------------------------------------------------
__global__ void median_pool(const float* __restrict__ xy, const float* __restrict__ orig,
                            float* __restrict__ proj) {
    int w = blockIdx.x * 4 + (threadIdx.x >> 6);
    int lane = threadIdx.x & 63;
    int n = w / (3 * HWP);
    int rem = w % (3 * HWP);
    int c = rem / HWP;
    int b = rem % HWP;
    const float* src = (c < 2) ? (xy + ((size_t)n * 2 + c) * H0 * W0)
                               : (orig + ((size_t)n * 4 + 3) * H0 * W0);
    int by = b / WW, bx = b % WW;
    int r = lane >> 3, col = lane & 7;
    float v = src[(by * 8 + r) * W0 + bx * 8 + col];
    #pragma unroll
    for (int k = 2; k <= 64; k <<= 1) {
        #pragma unroll
        for (int j2 = k >> 1; j2 >= 1; j2 >>= 1) {
            float p = __shfl_xor(v, j2, 64);
            bool dir = (lane & k) == 0;
            bool low = (lane & j2) == 0;
            v = (dir == low) ? fminf(v, p) : fmaxf(v, p);
        }
    }
    if (lane == 31) proj[(size_t)c * (NB * HWP) + (size_t)n * HWP + b] = v;
}

// ---------------------------------------------------------------------------
// 3) KNN — wave64/row. Pass A: squared distances s in regs + lane min (no
//    sqrt). M_s = 16th-smallest lane min (bitonic). Filter s <= M_test where
//    M_test inflates M_s past sqrt's rounding class (superset proof in notes).
//    Compact survivors; sqrt only them; one 64-wide u64 bitonic sort on
//    (d_bits<<32|idx); lanes 0..15 emit. Fallback = validated full path.
// ---------------------------------------------------------------------------
__global__ void __launch_bounds__(256) knn_kernel(const float* __restrict__ proj,
                                                  int* __restrict__ knn) {
#pragma clang fp contract(off)
    __shared__ float4 pts[HWP];                    // (x, y, z, sq) per candidate
    __shared__ unsigned long long sbuf[4][64];     // survivor keys per wave
    int n = blockIdx.y;
    const float* px = proj + (size_t)n * HWP;
    const float* py = proj + (size_t)NB * HWP + (size_t)n * HWP;
    const float* pz = proj + (size_t)2 * NB * HWP + (size_t)n * HWP;
    for (int t = threadIdx.x; t < HWP; t += 256) {
        float x = px[t], y = py[t], z = pz[t];
        float4 p;
        p.x = x; p.y = y; p.z = z;
        p.w = (x * x + y * y) + z * z;             // mirrors jnp.sum(proj*proj,-1)
        pts[t] = p;
    }
    __syncthreads();

    int wave = threadIdx.x >> 6;
    int lane = threadIdx.x & 63;
    int i = blockIdx.x * 4 + wave;                 // row (675*4 == 2700 exactly)
    float4 pi = pts[i];
    float xi = pi.x, yi = pi.y, zi = pi.z, sqi = pi.w;

    // ---- Pass A: squared distances (same s arithmetic as validated) ----
    float sd[NT];
    float mn = FLT_MAX;
    #pragma unroll
    for (int t = 0; t < NT; ++t) {
        int j = lane + t * 64;
        float s = FLT_MAX;
        if (j < HWP) {
            float4 pj = pts[j];
            float r = fmaf(zi, pj.z, fmaf(yi, pj.y, xi * pj.x));
            s = (sqi + pj.w) - 2.0f * r;
        }
        sd[t] = s;
        mn = fminf(mn, s);
    }

    // ---- Bitonic sort the 64 lane minima ascending; M_s = rank 15 ----
    float v = mn;
    #pragma unroll
    for (int k = 2; k <= 64; k <<= 1) {
        #pragma unroll
        for (int j2 = k >> 1; j2 >= 1; j2 >>= 1) {
            float p = __shfl_xor(v, j2, 64);
            bool dir = (lane & k) == 0;
            bool low = (lane & j2) == 0;
            v = (dir == low) ? fminf(v, p) : fmaxf(v, p);
        }
    }
    float M_s = __shfl(v, 15, 64);
    // slack past sqrt's rounding class; M_s<=0 -> keep all s<=0 (d==0 ties)
    float M_test = (M_s > 0.f) ? (M_s * 1.0000005f + 1e-37f) : 0.0f;

    // ---- Pass B: ballot-compact survivors (s-keys) into LDS ----
    int cnt = 0;
    #pragma unroll
    for (int t = 0; t < NT; ++t) {
        bool pred = sd[t] <= M_test;
        unsigned long long b = __ballot(pred);
        if (b) {
            int off = cnt + (int)__popcll(b & ((1ull << lane) - 1ull));
            if (pred && off < 64) {
                unsigned int j = (unsigned int)(lane + t * 64);
                sbuf[wave][off] =
                    ((unsigned long long)__float_as_uint(sd[t]) << 32) | j;
            }
            cnt += (int)__popcll(b);
        }
    }

    int myj = 0;
    if (cnt >= KNN && cnt <= 64) {
        // ---- sqrt survivors, 64-wide u64 bitonic sort on (d, idx) ----
        const unsigned long long INFK = ~0ull;
        unsigned long long key = INFK;
        if (lane < cnt) {
            unsigned long long ks = sbuf[wave][lane];
            float s = __uint_as_float((unsigned int)(ks >> 32));
            float d = sqrtf(fmaxf(s, 0.f));
            key = ((unsigned long long)__float_as_uint(d) << 32) | (ks & 0xffffffffull);
        }
        #pragma unroll
        for (int k = 2; k <= 64; k <<= 1) {
            #pragma unroll
            for (int j2 = k >> 1; j2 >= 1; j2 >>= 1) {
                unsigned long long p = __shfl_xor(key, j2, 64);
                bool dir = (lane & k) == 0;
                bool low = (lane & j2) == 0;
                bool keepmin = (dir == low);
                bool pless = p < key;
                key = (pless == keepmin) ? p : key;
            }
        }
        myj = (int)(unsigned int)(key & 0xffffffffull);
    } else {
        // ---- fallback: validated full scan + insert + merge ----
        float best[KNN]; int bidx[KNN];
        #pragma unroll
        for (int k = 0; k < KNN; ++k) { best[k] = FLT_MAX; bidx[k] = 0x7fffffff; }
        for (int j = lane; j < HWP; j += 64) {
            float4 pj = pts[j];
            float r = fmaf(zi, pj.z, fmaf(yi, pj.y, xi * pj.x));
            float s = (sqi + pj.w) - 2.0f * r;
            float dd = sqrtf(fmaxf(s, 0.f));
            if (dd < best[KNN - 1]) {
                float cd = dd; int ci = j;
                #pragma unroll
                for (int k = 0; k < KNN; ++k) {
                    bool lt = cd < best[k];
                    float tv = best[k]; int ti = bidx[k];
                    best[k] = lt ? cd : best[k];
                    bidx[k] = lt ? ci : bidx[k];
                    cd = lt ? tv : cd;
                    ci = lt ? ti : ci;
                }
            }
        }
        float hd = best[0]; int hj = bidx[0];
        #pragma unroll
        for (int t = 0; t < KNN; ++t) {
            float md = hd; int mj = hj;
            #pragma unroll
            for (int off = 32; off >= 1; off >>= 1) {
                float od = __shfl_xor(md, off, 64);
                int oj = __shfl_xor(mj, off, 64);
                if (od < md || (od == md && oj < mj)) { md = od; mj = oj; }
            }
            if (lane == t) myj = mj;
            bool win = (hd == md) && (hj == mj);
            if (win) {
                #pragma unroll
                for (int k = 0; k < KNN - 1; ++k) { best[k] = best[k + 1]; bidx[k] = bidx[k + 1]; }
                best[KNN - 1] = FLT_MAX; bidx[KNN - 1] = 0x7fffffff;
                hd = best[0]; hj = bidx[0];
            }
        }
    }
    if (lane < KNN)
        knn[((size_t)n * HWP + i) * KNN + lane] = myj;
}

// ---------------------------------------------------------------------------
// 4a) Split W (Wt[c][k], row-major) into bf16 hi/lo MFMA B-fragments:
//     wf[kc][ntile(8)][lane(64)][j(8)], n = ntile*16+(lane&15),
//     k = kc*32 + (lane>>4)*8 + j
// ---------------------------------------------------------------------------
template <int K>
__global__ void prep_wsplit(const float* __restrict__ Wt,
                            __bf16* __restrict__ wf_hi, __bf16* __restrict__ wf_lo) {
    int t = blockIdx.x * 256 + threadIdx.x;        // (K/32)*4096 threads
    int j = t & 7;
    int lane = (t >> 3) & 63;
    int nt = (t >> 9) & 7;
    int kc = t >> 12;
    int oc = nt * 16 + (lane & 15);
    int k = kc * 32 + (lane >> 4) * 8 + j;
    float v = Wt[(size_t)oc * K + k];
    __bf16 hi = (__bf16)v;
    wf_hi[t] = hi;
    wf_lo[t] = (__bf16)(v - (float)hi);
}

// ---------------------------------------------------------------------------
// 4b) GEMM + bias + PReLU on MFMA, split-bf16 (hi/lo, 3 MFMAs ~ fp32 grade).
//     Block = 32 rows x 128 cols, 4 waves: wave wn covers cols wn*32..+31.
//     A = [A0 | A1] (128 each) for K=256.
// ---------------------------------------------------------------------------
template <int K>
__global__ void __launch_bounds__(256) gemm_mfma_prelu(
    const float* __restrict__ A0, const float* __restrict__ A1,
    const __bf16* __restrict__ wf_hi, const __bf16* __restrict__ wf_lo,
    const float* __restrict__ bias, const float* __restrict__ alphap,
    float* __restrict__ out) {
    __shared__ __bf16 a_hi[32 * 40], a_lo[32 * 40];   // [row][k-chunk col], stride 40
    int r0 = blockIdx.x * 32;
    int tid = threadIdx.x;
    int wave = tid >> 6, lane = tid & 63;
    int quad = lane >> 4, lm = lane & 15;
    int wn = wave;
    f32x4 acc[2][2] = {};
    const bf16_8* wh8 = (const bf16_8*)wf_hi;
    const bf16_8* wl8 = (const bf16_8*)wf_lo;

    for (int kc = 0; kc < K / 32; ++kc) {
        __syncthreads();
        {   // stage 32 rows x 32 k fp32 -> hi/lo bf16
            int row = tid >> 3, c4 = (tid & 7) * 4;
            const float* src = (K == 256 && kc >= 4)
                ? &A1[((size_t)(r0 + row)) * 128 + (kc - 4) * 32 + c4]
                : &A0[((size_t)(r0 + row)) * 128 + kc * 32 + c4];
            float4 vv = *(const float4*)src;
            bf16_4 h4, l4;
            float vs[4] = {vv.x, vv.y, vv.z, vv.w};
            #pragma unroll
            for (int e = 0; e < 4; ++e) {
                __bf16 hi = (__bf16)vs[e];
                h4[e] = hi;
                l4[e] = (__bf16)(vs[e] - (float)hi);
            }
            *(bf16_4*)&a_hi[row * 40 + c4] = h4;
            *(bf16_4*)&a_lo[row * 40 + c4] = l4;
        }
        __syncthreads();
        bf16_8 ah[2], al[2], bh[2], bl[2];
        #pragma unroll
        for (int mt = 0; mt < 2; ++mt) {
            ah[mt] = *(const bf16_8*)&a_hi[(mt * 16 + lm) * 40 + quad * 8];
            al[mt] = *(const bf16_8*)&a_lo[(mt * 16 + lm) * 40 + quad * 8];
        }
        #pragma unroll
        for (int nt = 0; nt < 2; ++nt) {
            size_t idx = ((size_t)kc * 8 + (wn * 2 + nt)) * 64 + lane;
            bh[nt] = wh8[idx];
            bl[nt] = wl8[idx];
        }
        #pragma unroll
        for (int mt = 0; mt < 2; ++mt)
            #pragma unroll
            for (int nt = 0; nt < 2; ++nt) {
                acc[mt][nt] = __builtin_amdgcn_mfma_f32_16x16x32_bf16(ah[mt], bh[nt], acc[mt][nt], 0, 0, 0);
                acc[mt][nt] = __builtin_amdgcn_mfma_f32_16x16x32_bf16(ah[mt], bl[nt], acc[mt][nt], 0, 0, 0);
                acc[mt][nt] = __builtin_amdgcn_mfma_f32_16x16x32_bf16(al[mt], bh[nt], acc[mt][nt], 0, 0, 0);
            }
    }
    float alpha = alphap[0];
    #pragma unroll
    for (int mt = 0; mt < 2; ++mt) {
        int m0 = r0 + mt * 16 + quad * 4;
        #pragma unroll
        for (int nt = 0; nt < 2; ++nt) {
            int col = wn * 32 + nt * 16 + lm;
            float bb = bias[col];
            #pragma unroll
            for (int reg = 0; reg < 4; ++reg) {
                float vv = acc[mt][nt][reg] + bb;
                vv = (vv >= 0.f) ? vv : alpha * vv;
                out[((size_t)(m0 + reg)) * 128 + col] = vv;
            }
        }
    }
}

// ---------------------------------------------------------------------------
// 5) gather + mean over 16 neighbors
// ---------------------------------------------------------------------------
__global__ void gather_mean(const float* __restrict__ g, const int* __restrict__ knn,
                            float* __restrict__ m) {
    int tid = threadIdx.x;
    int rloc = tid >> 5, c4 = tid & 31;
    size_t row = (size_t)blockIdx.x * 8 + rloc;
    int n = (int)(row / HWP);
    const int* kn = knn + row * KNN;
    float4 acc = {0, 0, 0, 0};
    #pragma unroll
    for (int k = 0; k < KNN; ++k) {
        int j = kn[k];
        float4 v = *(const float4*)&g[((size_t)n * HWP + j) * 128 + c4 * 4];
        acc.x += v.x; acc.y += v.y; acc.z += v.z; acc.w += v.w;
    }
    const float s = 1.f / 16.f;
    float4 o = {acc.x * s, acc.y * s, acc.z * s, acc.w * s};
    *(float4*)&m[row * 128 + c4 * 4] = o;
}

// ---------------------------------------------------------------------------
// 6a) Pack concat(cnn_cl, h) -> zero-padded channel-last bf16 (N,47,68,256)
// ---------------------------------------------------------------------------
__global__ void pack_input(const float* __restrict__ cnn_cl, const float* __restrict__ h,
                           __bf16* __restrict__ pad_in) {
    int t = blockIdx.x * 256 + threadIdx.x;      // 818,176 threads, 8 ch each
    int cg = t & 31;
    int s = t >> 5;
    int q = s % 68; s /= 68;
    int p = s % 47;
    int n = s / 47;
    int y = p - 1, x = q - 1;
    bf16_8 v = {};
    if (y >= 0 && y < HH && x >= 0 && x < WW) {
        int c0 = cg * 8;
        const float* src = (c0 < 128)
            ? (cnn_cl + (((size_t)n * HWP + y * WW + x) * 128 + c0))
            : (h      + (((size_t)n * HWP + y * WW + x) * 128 + (c0 - 128)));
        float4 l0 = *(const float4*)&src[0];
        float4 l1 = *(const float4*)&src[4];
        v[0] = (__bf16)l0.x; v[1] = (__bf16)l0.y; v[2] = (__bf16)l0.z; v[3] = (__bf16)l0.w;
        v[4] = (__bf16)l1.x; v[5] = (__bf16)l1.y; v[6] = (__bf16)l1.z; v[7] = (__bf16)l1.w;
    }
    ((bf16_8*)pad_in)[t] = v;
}

// ---------------------------------------------------------------------------
// 6b) Swizzle conv weights into MFMA B-fragment order (validated round 3)
// ---------------------------------------------------------------------------
__global__ void prep_wfrag(const float* __restrict__ conv_w, __bf16* __restrict__ w_frag) {
    int t = blockIdx.x * 256 + threadIdx.x;      // 294,912 threads
    int j = t & 7;
    int lane = (t >> 3) & 63;
    int ntile = (t >> 9) & 7;
    int icc = (t >> 12) & 7;
    int tap = t >> 15;                            // 0..8
    int oc = ntile * 16 + (lane & 15);
    int ic = icc * 32 + (lane >> 4) * 8 + j;
    w_frag[t] = (__bf16)conv_w[((size_t)oc * 256 + ic) * 9 + tap];
}

// ---------------------------------------------------------------------------
// 6c) Conv 3x3 as implicit GEMM on MFMA (validated round 3)
// ---------------------------------------------------------------------------
__global__ void __launch_bounds__(256) conv_mfma(
    const __bf16* __restrict__ pad_in,   // (N,47,68,256)
    const __bf16* __restrict__ w_frag,   // fragment-ordered weights
    const float* __restrict__ bias,
    float* __restrict__ out) {           // (N,128,45,60)
    __shared__ __bf16 alds[3 * 66 * 32];         // [dy][px 0..65][ic 0..31]
    int y = blockIdx.x;
    int n = blockIdx.y;
    int tid = threadIdx.x;
    int wave = tid >> 6, lane = tid & 63;
    int wm = wave & 1, wn = wave >> 1;
    int quad = lane >> 4, lm = lane & 15;

    f32x4 acc[2][4] = {};
    const bf16_8* wf = (const bf16_8*)w_frag;

    for (int icc = 0; icc < 8; ++icc) {
        __syncthreads();
        for (int t = tid; t < 792; t += 256) {   // 3*66*4 x 16B
            int cq = t & 3;
            int xp = (t >> 2) % 66;
            int dy = (t >> 2) / 66;
            size_t src = (((size_t)n * 47 + (y + dy)) * 68 + xp) * 256 + icc * 32 + cq * 8;
            *(bf16_8*)&alds[(dy * 66 + xp) * 32 + cq * 8] = *(const bf16_8*)&pad_in[src];
        }
        __syncthreads();
        #pragma unroll
        for (int tap = 0; tap < 9; ++tap) {
            int ky = tap / 3, kx = tap % 3;
            bf16_8 b[4], a[2];
            #pragma unroll
            for (int nt = 0; nt < 4; ++nt)
                b[nt] = wf[(((tap * 8 + icc) * 8) + (wn * 4 + nt)) * 64 + lane];
            #pragma unroll
            for (int mt = 0; mt < 2; ++mt)
                a[mt] = *(const bf16_8*)&alds[(ky * 66 + (wm * 32 + mt * 16 + lm + kx)) * 32 + quad * 8];
            #pragma unroll
            for (int mt = 0; mt < 2; ++mt)
                #pragma unroll
                for (int nt = 0; nt < 4; ++nt)
                    acc[mt][nt] = __builtin_amdgcn_mfma_f32_16x16x32_bf16(
                        a[mt], b[nt], acc[mt][nt], 0, 0, 0);
        }
    }
    #pragma unroll
    for (int mt = 0; mt < 2; ++mt) {
        int x0 = wm * 32 + mt * 16 + quad * 4;
        if (x0 >= WW) continue;
        #pragma unroll
        for (int nt = 0; nt < 4; ++nt) {
            int oc = wn * 64 + nt * 16 + lm;
            float bb = bias[oc];
            f32x4 v = acc[mt][nt];
            v[0] += bb; v[1] += bb; v[2] += bb; v[3] += bb;
            *(f32x4*)&out[(((size_t)n * 128 + oc) * HH + y) * WW + x0] = v;
        }
    }
}

// ---------------------------------------------------------------------------
extern "C" void kernel_launch(void* const* d_in, const int* in_sizes, int n_in,
                              void* d_out, int out_size, void* d_ws, size_t ws_size,
                              hipStream_t stream) {
    const float* cnn    = (const float*)d_in[0];
    const float* orig   = (const float*)d_in[1];
    const float* xy     = (const float*)d_in[2];
    const float* g_w0   = (const float*)d_in[3];
    const float* g_b0   = (const float*)d_in[4];
    const float* g_a0   = (const float*)d_in[5];
    const float* g_w1   = (const float*)d_in[6];
    const float* g_b1   = (const float*)d_in[7];
    const float* g_a1   = (const float*)d_in[8];
    const float* q_w    = (const float*)d_in[9];
    const float* q_b    = (const float*)d_in[10];
    const float* q_a    = (const float*)d_in[11];
    const float* conv_w = (const float*)d_in[12];
    const float* conv_b = (const float*)d_in[13];
    float* out = (float*)d_out;

    float* ws = (float*)d_ws;
    const size_t S = (size_t)NB * HWP * CC;     // 2,764,800
    float* cnn_cl = ws;
    float* h      = ws + S;
    float* tg     = ws + 2 * S;
    float* m      = ws + 3 * S;
    float* proj   = ws + 4 * S;                 // 3 * N*HW
    int*   knn    = (int*)(ws + 4 * S + (size_t)3 * NB * HWP);
    // weight hi/lo fragment buffers (live through the GNN)
    __bf16* wfb   = (__bf16*)(ws + 4 * S + (size_t)3 * NB * HWP + (size_t)MROWS * KNN);
    __bf16* g0h = wfb;            __bf16* g0l = wfb + 16384;
    __bf16* g1h = wfb + 32768;    __bf16* g1l = wfb + 49152;
    __bf16* qh  = wfb + 65536;    __bf16* ql  = wfb + 98304;
    // dead after the GNN: tg/m regions reused for conv staging
    __bf16* pad_in = (__bf16*)(ws + 2 * S);                    // 6,545,408 bf16
    __bf16* w_frag = (__bf16*)(ws + 3 * S + 600000);           // 294,912 bf16

    transpose_cl<<<dim3(85, 4, NB), 256, 0, stream>>>(cnn, cnn_cl);
    median_pool<<<16200, 256, 0, stream>>>(xy, orig, proj);
    knn_kernel<<<dim3(675, NB), 256, 0, stream>>>(proj, knn);

    prep_wsplit<128><<<64, 256, 0, stream>>>(g_w0, g0h, g0l);
    prep_wsplit<128><<<64, 256, 0, stream>>>(g_w1, g1h, g1l);
    prep_wsplit<256><<<128, 256, 0, stream>>>(q_w, qh, ql);

    // GNN iteration 1 (h = cnn_cl)
    gemm_mfma_prelu<128><<<675, 256, 0, stream>>>(cnn_cl, nullptr, g0h, g0l, g_b0, g_a0, tg);
    gemm_mfma_prelu<128><<<675, 256, 0, stream>>>(tg, nullptr, g1h, g1l, g_b1, g_a1, tg);
    gather_mean<<<2700, 256, 0, stream>>>(tg, knn, m);
    gemm_mfma_prelu<256><<<675, 256, 0, stream>>>(cnn_cl, m, qh, ql, q_b, q_a, h);

    // GNN iteration 2
    gemm_mfma_prelu<128><<<675, 256, 0, stream>>>(h, nullptr, g0h, g0l, g_b0, g_a0, tg);
    gemm_mfma_prelu<128><<<675, 256, 0, stream>>>(tg, nullptr, g1h, g1l, g_b1, g_a1, tg);
    gather_mean<<<2700, 256, 0, stream>>>(tg, knn, m);
    gemm_mfma_prelu<256><<<675, 256, 0, stream>>>(h, m, qh, ql, q_b, q_a, h);

    // Conv: pack inputs (bf16, padded), swizzle weights, MFMA conv
    pack_input<<<3196, 256, 0, stream>>>(cnn_cl, h, pad_in);
    prep_wfrag<<<1152, 256, 0, stream>>>(conv_w, w_frag);
    conv_mfma<<<dim3(HH, NB), 256, 0, stream>>>(pad_in, w_frag, conv_b, out);
}

// Round 6
// 310.395 us; speedup vs baseline: 6.6564x; 1.1080x over previous
//
#include <hip/hip_runtime.h>
#include <cfloat>
#include <cmath>

#define NB 8
#define CC 128
#define HH 45
#define WW 60
#define HWP 2700      // H*W
#define KNN 16
#define H0 360
#define W0 480
#define NT 43         // ceil(2700/64) candidates per lane
#define MROWS 21600   // NB * HWP

typedef __bf16 bf16_8 __attribute__((ext_vector_type(8)));
typedef __bf16 bf16_4 __attribute__((ext_vector_type(4)));
typedef float  f32x4  __attribute__((ext_vector_type(4)));

// ---------------------------------------------------------------------------
// 1) Transpose (N,128,HW) -> (N,HW,128) channel-last
// ---------------------------------------------------------------------------
__global__ void transpose_cl(const float* __restrict__ in, float* __restrict__ out) {
    __shared__ float tile[32][33];
    int n = blockIdx.z;
    int c0 = blockIdx.y * 32;
    int p0 = blockIdx.x * 32;
    int tx = threadIdx.x & 31, ty = threadIdx.x >> 5;   // 32 x 8
    #pragma unroll
    for (int r = 0; r < 32; r += 8) {
        int c = c0 + ty + r, p = p0 + tx;
        tile[ty + r][tx] = (p < HWP) ? in[((size_t)n * CC + c) * HWP + p] : 0.f;
    }
    __syncthreads();
    #pragma unroll
    for (int r = 0; r < 32; r += 8) {
        int p = p0 + ty + r, c = c0 + tx;
        if (p < HWP) out[((size_t)n * HWP + p) * CC + c] = tile[tx][ty + r];
    }
}

// ---------------------------------------------------------------------------
// 2) Median pool 8x8: bitonic sort 64 lanes ascending, lane 31 = lower median
// ---------------------------------------------------------------------------
__global__ void median_pool(const float* __restrict__ xy, const float* __restrict__ orig,
                            float* __restrict__ proj) {
    int w = blockIdx.x * 4 + (threadIdx.x >> 6);
    int lane = threadIdx.x & 63;
    int n = w / (3 * HWP);
    int rem = w % (3 * HWP);
    int c = rem / HWP;
    int b = rem % HWP;
    const float* src = (c < 2) ? (xy + ((size_t)n * 2 + c) * H0 * W0)
                               : (orig + ((size_t)n * 4 + 3) * H0 * W0);
    int by = b / WW, bx = b % WW;
    int r = lane >> 3, col = lane & 7;
    float v = src[(by * 8 + r) * W0 + bx * 8 + col];
    #pragma unroll
    for (int k = 2; k <= 64; k <<= 1) {
        #pragma unroll
        for (int j2 = k >> 1; j2 >= 1; j2 >>= 1) {
            float p = __shfl_xor(v, j2, 64);
            bool dir = (lane & k) == 0;
            bool low = (lane & j2) == 0;
            v = (dir == low) ? fminf(v, p) : fmaxf(v, p);
        }
    }
    if (lane == 31) proj[(size_t)c * (NB * HWP) + (size_t)n * HWP + b] = v;
}

// ---------------------------------------------------------------------------
// 3) KNN — validated round-5 algorithm, now 512-thr blocks (8 rows/block):
//    pts staging amortized over 8 rows; VGPR (not LDS) sets occupancy.
// ---------------------------------------------------------------------------
__global__ void __launch_bounds__(512) knn_kernel(const float* __restrict__ proj,
                                                  int* __restrict__ knn) {
#pragma clang fp contract(off)
    __shared__ float4 pts[HWP];                    // (x, y, z, sq) per candidate
    __shared__ unsigned long long sbuf[8][64];     // survivor keys per wave
    int n = blockIdx.y;
    const float* px = proj + (size_t)n * HWP;
    const float* py = proj + (size_t)NB * HWP + (size_t)n * HWP;
    const float* pz = proj + (size_t)2 * NB * HWP + (size_t)n * HWP;
    for (int t = threadIdx.x; t < HWP; t += 512) {
        float x = px[t], y = py[t], z = pz[t];
        float4 p;
        p.x = x; p.y = y; p.z = z;
        p.w = (x * x + y * y) + z * z;             // mirrors jnp.sum(proj*proj,-1)
        pts[t] = p;
    }
    __syncthreads();

    int wave = threadIdx.x >> 6;
    int lane = threadIdx.x & 63;
    int i = blockIdx.x * 8 + wave;                 // row (338*8 >= 2700)
    if (i >= HWP) return;                          // no syncs after this point
    float4 pi = pts[i];
    float xi = pi.x, yi = pi.y, zi = pi.z, sqi = pi.w;

    // ---- Pass A: squared distances (same s arithmetic as validated) ----
    float sd[NT];
    float mn = FLT_MAX;
    #pragma unroll
    for (int t = 0; t < NT; ++t) {
        int j = lane + t * 64;
        float s = FLT_MAX;
        if (j < HWP) {
            float4 pj = pts[j];
            float r = fmaf(zi, pj.z, fmaf(yi, pj.y, xi * pj.x));
            s = (sqi + pj.w) - 2.0f * r;
        }
        sd[t] = s;
        mn = fminf(mn, s);
    }

    // ---- Bitonic sort the 64 lane minima ascending; M_s = rank 15 ----
    float v = mn;
    #pragma unroll
    for (int k = 2; k <= 64; k <<= 1) {
        #pragma unroll
        for (int j2 = k >> 1; j2 >= 1; j2 >>= 1) {
            float p = __shfl_xor(v, j2, 64);
            bool dir = (lane & k) == 0;
            bool low = (lane & j2) == 0;
            v = (dir == low) ? fminf(v, p) : fmaxf(v, p);
        }
    }
    float M_s = __shfl(v, 15, 64);
    float M_test = (M_s > 0.f) ? (M_s * 1.0000005f + 1e-37f) : 0.0f;

    // ---- Pass B: ballot-compact survivors (s-keys) into LDS ----
    int cnt = 0;
    #pragma unroll
    for (int t = 0; t < NT; ++t) {
        bool pred = sd[t] <= M_test;
        unsigned long long b = __ballot(pred);
        if (b) {
            int off = cnt + (int)__popcll(b & ((1ull << lane) - 1ull));
            if (pred && off < 64) {
                unsigned int j = (unsigned int)(lane + t * 64);
                sbuf[wave][off] =
                    ((unsigned long long)__float_as_uint(sd[t]) << 32) | j;
            }
            cnt += (int)__popcll(b);
        }
    }

    int myj = 0;
    if (cnt >= KNN && cnt <= 64) {
        // ---- sqrt survivors, 64-wide u64 bitonic sort on (d, idx) ----
        const unsigned long long INFK = ~0ull;
        unsigned long long key = INFK;
        if (lane < cnt) {
            unsigned long long ks = sbuf[wave][lane];
            float s = __uint_as_float((unsigned int)(ks >> 32));
            float d = sqrtf(fmaxf(s, 0.f));
            key = ((unsigned long long)__float_as_uint(d) << 32) | (ks & 0xffffffffull);
        }
        #pragma unroll
        for (int k = 2; k <= 64; k <<= 1) {
            #pragma unroll
            for (int j2 = k >> 1; j2 >= 1; j2 >>= 1) {
                unsigned long long p = __shfl_xor(key, j2, 64);
                bool dir = (lane & k) == 0;
                bool low = (lane & j2) == 0;
                bool keepmin = (dir == low);
                bool pless = p < key;
                key = (pless == keepmin) ? p : key;
            }
        }
        myj = (int)(unsigned int)(key & 0xffffffffull);
    } else {
        // ---- fallback: validated full scan + insert + merge ----
        float best[KNN]; int bidx[KNN];
        #pragma unroll
        for (int k = 0; k < KNN; ++k) { best[k] = FLT_MAX; bidx[k] = 0x7fffffff; }
        for (int j = lane; j < HWP; j += 64) {
            float4 pj = pts[j];
            float r = fmaf(zi, pj.z, fmaf(yi, pj.y, xi * pj.x));
            float s = (sqi + pj.w) - 2.0f * r;
            float dd = sqrtf(fmaxf(s, 0.f));
            if (dd < best[KNN - 1]) {
                float cd = dd; int ci = j;
                #pragma unroll
                for (int k = 0; k < KNN; ++k) {
                    bool lt = cd < best[k];
                    float tv = best[k]; int ti = bidx[k];
                    best[k] = lt ? cd : best[k];
                    bidx[k] = lt ? ci : bidx[k];
                    cd = lt ? tv : cd;
                    ci = lt ? ti : ci;
                }
            }
        }
        float hd = best[0]; int hj = bidx[0];
        #pragma unroll
        for (int t = 0; t < KNN; ++t) {
            float md = hd; int mj = hj;
            #pragma unroll
            for (int off = 32; off >= 1; off >>= 1) {
                float od = __shfl_xor(md, off, 64);
                int oj = __shfl_xor(mj, off, 64);
                if (od < md || (od == md && oj < mj)) { md = od; mj = oj; }
            }
            if (lane == t) myj = mj;
            bool win = (hd == md) && (hj == mj);
            if (win) {
                #pragma unroll
                for (int k = 0; k < KNN - 1; ++k) { best[k] = best[k + 1]; bidx[k] = bidx[k + 1]; }
                best[KNN - 1] = FLT_MAX; bidx[KNN - 1] = 0x7fffffff;
                hd = best[0]; hj = bidx[0];
            }
        }
    }
    if (lane < KNN)
        knn[((size_t)n * HWP + i) * KNN + lane] = myj;
}

// ---------------------------------------------------------------------------
// 4) One prep kernel: split g0/g1/q weights into hi/lo MFMA fragments +
//    swizzle conv weights into B-fragment order.
// ---------------------------------------------------------------------------
template <int K>
__device__ __forceinline__ void wsplit_body(const float* __restrict__ Wt,
                                            __bf16* __restrict__ wh,
                                            __bf16* __restrict__ wl,
                                            int bx, int tid) {
    int t = bx * 256 + tid;
    int j = t & 7;
    int lane = (t >> 3) & 63;
    int nt = (t >> 9) & 7;
    int kc = t >> 12;
    int oc = nt * 16 + (lane & 15);
    int k = kc * 32 + (lane >> 4) * 8 + j;
    float v = Wt[(size_t)oc * K + k];
    __bf16 hi = (__bf16)v;
    wh[t] = hi;
    wl[t] = (__bf16)(v - (float)hi);
}

__global__ void prep_all(const float* __restrict__ g_w0, const float* __restrict__ g_w1,
                         const float* __restrict__ q_w, const float* __restrict__ conv_w,
                         __bf16* __restrict__ g0h, __bf16* __restrict__ g0l,
                         __bf16* __restrict__ g1h, __bf16* __restrict__ g1l,
                         __bf16* __restrict__ qh, __bf16* __restrict__ ql,
                         __bf16* __restrict__ w_frag) {
    int bx = blockIdx.x, tid = threadIdx.x;
    if (bx < 64)        wsplit_body<128>(g_w0, g0h, g0l, bx, tid);
    else if (bx < 128)  wsplit_body<128>(g_w1, g1h, g1l, bx - 64, tid);
    else if (bx < 256)  wsplit_body<256>(q_w, qh, ql, bx - 128, tid);
    else {
        int t = (bx - 256) * 256 + tid;              // 294,912
        int j = t & 7;
        int lane = (t >> 3) & 63;
        int ntile = (t >> 9) & 7;
        int icc = (t >> 12) & 7;
        int tap = t >> 15;
        int oc = ntile * 16 + (lane & 15);
        int ic = icc * 32 + (lane >> 4) * 8 + j;
        w_frag[t] = (__bf16)conv_w[((size_t)oc * 256 + ic) * 9 + tap];
    }
}

// ---------------------------------------------------------------------------
// 5) Shared GEMM layer: 32 px x 128 oc, A-operand = weights (M=oc), B =
//    activations from LDS fp32 [pix][132] split hi/lo in-register.
//    D: col = pix (lane&15), rows = 4 consecutive oc -> float4-friendly.
// ---------------------------------------------------------------------------
__device__ __forceinline__ void layer_32x128(
    const float* __restrict__ src,                 // LDS [32][132] fp32
    const __bf16* __restrict__ wh, const __bf16* __restrict__ wl,
    int wave, int lane, int kc_base, f32x4 acc[2][2]) {
    int quad = lane >> 4, lm = lane & 15;
    const bf16_8* wh8 = (const bf16_8*)wh;
    const bf16_8* wl8 = (const bf16_8*)wl;
    #pragma unroll
    for (int kc = 0; kc < 4; ++kc) {
        bf16_8 bh[2], bl[2];
        #pragma unroll
        for (int nt = 0; nt < 2; ++nt) {
            const float* p = &src[(nt * 16 + lm) * 132 + kc * 32 + quad * 8];
            float4 v0 = *(const float4*)p;
            float4 v1 = *(const float4*)(p + 4);
            float vs[8] = {v0.x, v0.y, v0.z, v0.w, v1.x, v1.y, v1.z, v1.w};
            #pragma unroll
            for (int e = 0; e < 8; ++e) {
                __bf16 hi = (__bf16)vs[e];
                bh[nt][e] = hi;
                bl[nt][e] = (__bf16)(vs[e] - (float)hi);
            }
        }
        bf16_8 ah[2], al[2];
        #pragma unroll
        for (int mt = 0; mt < 2; ++mt) {
            size_t idx = ((size_t)(kc_base + kc) * 8 + (wave * 2 + mt)) * 64 + lane;
            ah[mt] = wh8[idx];
            al[mt] = wl8[idx];
        }
        #pragma unroll
        for (int mt = 0; mt < 2; ++mt)
            #pragma unroll
            for (int nt = 0; nt < 2; ++nt) {
                acc[mt][nt] = __builtin_amdgcn_mfma_f32_16x16x32_bf16(ah[mt], bh[nt], acc[mt][nt], 0, 0, 0);
                acc[mt][nt] = __builtin_amdgcn_mfma_f32_16x16x32_bf16(ah[mt], bl[nt], acc[mt][nt], 0, 0, 0);
                acc[mt][nt] = __builtin_amdgcn_mfma_f32_16x16x32_bf16(al[mt], bh[nt], acc[mt][nt], 0, 0, 0);
            }
    }
}

// ---------------------------------------------------------------------------
// 5a) Fused g-MLP: tgb = prelu(g1(prelu(g0(A)))) as bf16, intermediate in LDS
// ---------------------------------------------------------------------------
__global__ void __launch_bounds__(256) fused_g(
    const float* __restrict__ Ain,
    const __bf16* __restrict__ w0h, const __bf16* __restrict__ w0l,
    const float* __restrict__ b0, const float* __restrict__ a0p,
    const __bf16* __restrict__ w1h, const __bf16* __restrict__ w1l,
    const float* __restrict__ b1, const float* __restrict__ a1p,
    __bf16* __restrict__ tgb) {
    __shared__ float albuf[32 * 132];
    __shared__ float inter[32 * 132];
    int r0 = blockIdx.x * 32;
    int tid = threadIdx.x;
    int wave = tid >> 6, lane = tid & 63;
    int quad = lane >> 4, lm = lane & 15;
    for (int t = tid; t < 1024; t += 256) {
        int row = t >> 5, c4 = (t & 31) * 4;
        *(float4*)&albuf[row * 132 + c4] = *(const float4*)&Ain[(size_t)(r0 + row) * 128 + c4];
    }
    __syncthreads();
    // layer 0
    {
        f32x4 acc[2][2] = {};
        layer_32x128(albuf, w0h, w0l, wave, lane, 0, acc);
        float alpha = a0p[0];
        #pragma unroll
        for (int mt = 0; mt < 2; ++mt) {
            int oc0 = wave * 32 + mt * 16 + quad * 4;
            float4 bb = *(const float4*)&b0[oc0];
            float bv[4] = {bb.x, bb.y, bb.z, bb.w};
            #pragma unroll
            for (int nt = 0; nt < 2; ++nt) {
                float4 o;
                float* op = (float*)&o;
                #pragma unroll
                for (int reg = 0; reg < 4; ++reg) {
                    float vv = acc[mt][nt][reg] + bv[reg];
                    op[reg] = (vv >= 0.f) ? vv : alpha * vv;
                }
                *(float4*)&inter[(nt * 16 + lm) * 132 + oc0] = o;
            }
        }
    }
    __syncthreads();
    // layer 1
    {
        f32x4 acc[2][2] = {};
        layer_32x128(inter, w1h, w1l, wave, lane, 0, acc);
        float alpha = a1p[0];
        #pragma unroll
        for (int mt = 0; mt < 2; ++mt) {
            int oc0 = wave * 32 + mt * 16 + quad * 4;
            float4 bb = *(const float4*)&b1[oc0];
            float bv[4] = {bb.x, bb.y, bb.z, bb.w};
            #pragma unroll
            for (int nt = 0; nt < 2; ++nt) {
                bf16_4 o;
                #pragma unroll
                for (int reg = 0; reg < 4; ++reg) {
                    float vv = acc[mt][nt][reg] + bv[reg];
                    vv = (vv >= 0.f) ? vv : alpha * vv;
                    o[reg] = (__bf16)vv;
                }
                *(bf16_4*)&tgb[(size_t)(r0 + nt * 16 + lm) * 128 + oc0] = o;
            }
        }
    }
}

// ---------------------------------------------------------------------------
// 5b) Fused gather-mean + q-GEMM: h_out = prelu([A | mean16(tgb)] @ q^T + b)
// ---------------------------------------------------------------------------
__global__ void __launch_bounds__(256) fused_q(
    const float* __restrict__ Ain, const __bf16* __restrict__ tgb,
    const int* __restrict__ knn_idx,
    const __bf16* __restrict__ qh, const __bf16* __restrict__ ql,
    const float* __restrict__ qb, const float* __restrict__ qap,
    float* __restrict__ hout) {
    __shared__ float hlds[32 * 132];
    __shared__ float mlds[32 * 132];
    int r0 = blockIdx.x * 32;
    int tid = threadIdx.x;
    int wave = tid >> 6, lane = tid & 63;
    int quad = lane >> 4, lm = lane & 15;
    for (int t = tid; t < 1024; t += 256) {
        int row = t >> 5, c4 = (t & 31) * 4;
        *(float4*)&hlds[row * 132 + c4] = *(const float4*)&Ain[(size_t)(r0 + row) * 128 + c4];
    }
    {   // gather + mean: thread handles (pix, oct0) and (pix, oct0+1)
        int pix = tid >> 3;
        int oct0 = (tid & 7) * 2;
        int grow = r0 + pix;
        int nimg = grow / HWP;
        const int* kn = knn_idx + (size_t)grow * KNN;
        const __bf16* tbase = tgb + ((size_t)nimg * HWP) * 128;
        float a0[8] = {}, a1[8] = {};
        #pragma unroll
        for (int k = 0; k < KNN; ++k) {
            int j = kn[k];
            const __bf16* srcp = tbase + (size_t)j * 128 + oct0 * 8;
            bf16_8 v0 = *(const bf16_8*)srcp;
            bf16_8 v1 = *(const bf16_8*)(srcp + 8);
            #pragma unroll
            for (int e = 0; e < 8; ++e) { a0[e] += (float)v0[e]; a1[e] += (float)v1[e]; }
        }
        const float s = 1.f / 16.f;
        float* dst = &mlds[pix * 132 + oct0 * 8];
        float4 o0 = {a0[0] * s, a0[1] * s, a0[2] * s, a0[3] * s};
        float4 o1 = {a0[4] * s, a0[5] * s, a0[6] * s, a0[7] * s};
        float4 o2 = {a1[0] * s, a1[1] * s, a1[2] * s, a1[3] * s};
        float4 o3 = {a1[4] * s, a1[5] * s, a1[6] * s, a1[7] * s};
        *(float4*)(dst) = o0; *(float4*)(dst + 4) = o1;
        *(float4*)(dst + 8) = o2; *(float4*)(dst + 12) = o3;
    }
    __syncthreads();
    f32x4 acc[2][2] = {};
    layer_32x128(hlds, qh, ql, wave, lane, 0, acc);   // k 0..127 (h part)
    layer_32x128(mlds, qh, ql, wave, lane, 4, acc);   // k 128..255 (m part)
    float alpha = qap[0];
    #pragma unroll
    for (int mt = 0; mt < 2; ++mt) {
        int oc0 = wave * 32 + mt * 16 + quad * 4;
        float4 bb = *(const float4*)&qb[oc0];
        float bv[4] = {bb.x, bb.y, bb.z, bb.w};
        #pragma unroll
        for (int nt = 0; nt < 2; ++nt) {
            float4 o;
            float* op = (float*)&o;
            #pragma unroll
            for (int reg = 0; reg < 4; ++reg) {
                float vv = acc[mt][nt][reg] + bv[reg];
                op[reg] = (vv >= 0.f) ? vv : alpha * vv;
            }
            *(float4*)&hout[(size_t)(r0 + nt * 16 + lm) * 128 + oc0] = o;
        }
    }
}

// ---------------------------------------------------------------------------
// 6a) Pack concat(cnn_cl, h) -> zero-padded channel-last bf16 (N,47,68,256)
// ---------------------------------------------------------------------------
__global__ void pack_input(const float* __restrict__ cnn_cl, const float* __restrict__ h,
                           __bf16* __restrict__ pad_in) {
    int t = blockIdx.x * 256 + threadIdx.x;      // 818,176 threads, 8 ch each
    int cg = t & 31;
    int s = t >> 5;
    int q = s % 68; s /= 68;
    int p = s % 47;
    int n = s / 47;
    int y = p - 1, x = q - 1;
    bf16_8 v = {};
    if (y >= 0 && y < HH && x >= 0 && x < WW) {
        int c0 = cg * 8;
        const float* src = (c0 < 128)
            ? (cnn_cl + (((size_t)n * HWP + y * WW + x) * 128 + c0))
            : (h      + (((size_t)n * HWP + y * WW + x) * 128 + (c0 - 128)));
        float4 l0 = *(const float4*)&src[0];
        float4 l1 = *(const float4*)&src[4];
        v[0] = (__bf16)l0.x; v[1] = (__bf16)l0.y; v[2] = (__bf16)l0.z; v[3] = (__bf16)l0.w;
        v[4] = (__bf16)l1.x; v[5] = (__bf16)l1.y; v[6] = (__bf16)l1.z; v[7] = (__bf16)l1.w;
    }
    ((bf16_8*)pad_in)[t] = v;
}

// ---------------------------------------------------------------------------
// 6b) Conv 3x3 as implicit GEMM on MFMA (validated round 3)
// ---------------------------------------------------------------------------
__global__ void __launch_bounds__(256) conv_mfma(
    const __bf16* __restrict__ pad_in,   // (N,47,68,256)
    const __bf16* __restrict__ w_frag,   // fragment-ordered weights
    const float* __restrict__ bias,
    float* __restrict__ out) {           // (N,128,45,60)
    __shared__ __bf16 alds[3 * 66 * 32];         // [dy][px 0..65][ic 0..31]
    int y = blockIdx.x;
    int n = blockIdx.y;
    int tid = threadIdx.x;
    int wave = tid >> 6, lane = tid & 63;
    int wm = wave & 1, wn = wave >> 1;
    int quad = lane >> 4, lm = lane & 15;

    f32x4 acc[2][4] = {};
    const bf16_8* wf = (const bf16_8*)w_frag;

    for (int icc = 0; icc < 8; ++icc) {
        __syncthreads();
        for (int t = tid; t < 792; t += 256) {   // 3*66*4 x 16B
            int cq = t & 3;
            int xp = (t >> 2) % 66;
            int dy = (t >> 2) / 66;
            size_t src = (((size_t)n * 47 + (y + dy)) * 68 + xp) * 256 + icc * 32 + cq * 8;
            *(bf16_8*)&alds[(dy * 66 + xp) * 32 + cq * 8] = *(const bf16_8*)&pad_in[src];
        }
        __syncthreads();
        #pragma unroll
        for (int tap = 0; tap < 9; ++tap) {
            int ky = tap / 3, kx = tap % 3;
            bf16_8 b[4], a[2];
            #pragma unroll
            for (int nt = 0; nt < 4; ++nt)
                b[nt] = wf[(((tap * 8 + icc) * 8) + (wn * 4 + nt)) * 64 + lane];
            #pragma unroll
            for (int mt = 0; mt < 2; ++mt)
                a[mt] = *(const bf16_8*)&alds[(ky * 66 + (wm * 32 + mt * 16 + lm + kx)) * 32 + quad * 8];
            #pragma unroll
            for (int mt = 0; mt < 2; ++mt)
                #pragma unroll
                for (int nt = 0; nt < 4; ++nt)
                    acc[mt][nt] = __builtin_amdgcn_mfma_f32_16x16x32_bf16(
                        a[mt], b[nt], acc[mt][nt], 0, 0, 0);
        }
    }
    #pragma unroll
    for (int mt = 0; mt < 2; ++mt) {
        int x0 = wm * 32 + mt * 16 + quad * 4;
        if (x0 >= WW) continue;
        #pragma unroll
        for (int nt = 0; nt < 4; ++nt) {
            int oc = wn * 64 + nt * 16 + lm;
            float bb = bias[oc];
            f32x4 v = acc[mt][nt];
            v[0] += bb; v[1] += bb; v[2] += bb; v[3] += bb;
            *(f32x4*)&out[(((size_t)n * 128 + oc) * HH + y) * WW + x0] = v;
        }
    }
}

// ---------------------------------------------------------------------------
extern "C" void kernel_launch(void* const* d_in, const int* in_sizes, int n_in,
                              void* d_out, int out_size, void* d_ws, size_t ws_size,
                              hipStream_t stream) {
    const float* cnn    = (const float*)d_in[0];
    const float* orig   = (const float*)d_in[1];
    const float* xy     = (const float*)d_in[2];
    const float* g_w0   = (const float*)d_in[3];
    const float* g_b0   = (const float*)d_in[4];
    const float* g_a0   = (const float*)d_in[5];
    const float* g_w1   = (const float*)d_in[6];
    const float* g_b1   = (const float*)d_in[7];
    const float* g_a1   = (const float*)d_in[8];
    const float* q_w    = (const float*)d_in[9];
    const float* q_b    = (const float*)d_in[10];
    const float* q_a    = (const float*)d_in[11];
    const float* conv_w = (const float*)d_in[12];
    const float* conv_b = (const float*)d_in[13];
    float* out = (float*)d_out;

    float* ws = (float*)d_ws;
    const size_t S = (size_t)MROWS * CC;        // 2,764,800
    float*  cnn_cl = ws;                        // [0, S)
    float*  h      = ws + S;                    // [S, 2S)
    float*  base   = ws + 2 * S;
    __bf16* tgb    = (__bf16*)base;             // MROWS*128 bf16 = 1,382,400 fl
    float*  proj   = base + 1382400;            // 64,800 fl
    int*    knn_i  = (int*)(base + 1382400 + 64800);          // 345,600 slots
    __bf16* wfb    = (__bf16*)(base + 1382400 + 64800 + 345600);
    __bf16* g0h = wfb;            __bf16* g0l = wfb + 16384;
    __bf16* g1h = wfb + 32768;    __bf16* g1l = wfb + 49152;
    __bf16* qh  = wfb + 65536;    __bf16* ql  = wfb + 98304;  // 131,072 bf16
    __bf16* w_frag = wfb + 131072;                            // 294,912 bf16
    __bf16* pad_in = w_frag + 294912;                         // 6,545,408 bf16

    transpose_cl<<<dim3(85, 4, NB), 256, 0, stream>>>(cnn, cnn_cl);
    median_pool<<<16200, 256, 0, stream>>>(xy, orig, proj);
    knn_kernel<<<dim3(338, NB), 512, 0, stream>>>(proj, knn_i);
    prep_all<<<1408, 256, 0, stream>>>(g_w0, g_w1, q_w, conv_w,
                                       g0h, g0l, g1h, g1l, qh, ql, w_frag);

    // GNN iteration 1 (h = cnn_cl)
    fused_g<<<675, 256, 0, stream>>>(cnn_cl, g0h, g0l, g_b0, g_a0,
                                     g1h, g1l, g_b1, g_a1, tgb);
    fused_q<<<675, 256, 0, stream>>>(cnn_cl, tgb, knn_i, qh, ql, q_b, q_a, h);

    // GNN iteration 2
    fused_g<<<675, 256, 0, stream>>>(h, g0h, g0l, g_b0, g_a0,
                                     g1h, g1l, g_b1, g_a1, tgb);
    fused_q<<<675, 256, 0, stream>>>(h, tgb, knn_i, qh, ql, q_b, q_a, h);

    // Conv epilogue
    pack_input<<<3196, 256, 0, stream>>>(cnn_cl, h, pad_in);
    conv_mfma<<<dim3(HH, NB), 256, 0, stream>>>(pad_in, w_frag, conv_b, out);
}